// Round 10
// baseline (477.083 us; speedup 1.0000x reference)
//
#include <hip/hip_runtime.h>
#include <hip/hip_fp16.h>
#include <cstdint>

#define N_NODES 50000
#define E_EDGES 800000
#define HC 256           // H*C
#define B_GR 64
#define OUT_DIM 10
#define SLOPE 0.2f
#define NBLK_SCAN ((N_NODES + 255) / 256)   // 196

using f16x8 = __attribute__((ext_vector_type(8))) _Float16;
using f32x4 = __attribute__((ext_vector_type(4))) float;

#define GLOAD_LDS16(gsrc, ldst) \
    __builtin_amdgcn_global_load_lds((const __attribute__((address_space(1))) void*)(gsrc), \
        (__attribute__((address_space(3))) void*)(ldst), 16, 0, 0)

// ---------------- prep: x->hi/lo; W0/1/2 -> fragment-major hi/lo; cnt=1 -------
__device__ inline void wsplit_one(const float* W, _Float16* wh, _Float16* wl,
                                  int K, int i) {
    int k = i >> 8, n = i & 255;
    float v = W[i];
    _Float16 h = (_Float16)v;
    _Float16 l = (_Float16)(v - (float)h);
    int oidx = ((((k >> 5) * 256 + n) * 4) + ((k >> 3) & 3)) * 8 + (k & 7);
    wh[oidx] = h;
    wl[oidx] = l;
}

__global__ void prep_split(const float* __restrict__ x,
        _Float16* __restrict__ xhi, _Float16* __restrict__ xlo,
        const float* __restrict__ W0, _Float16* __restrict__ w0h, _Float16* __restrict__ w0l,
        const float* __restrict__ W1, _Float16* __restrict__ w1h, _Float16* __restrict__ w1l,
        const float* __restrict__ W2, _Float16* __restrict__ w2h, _Float16* __restrict__ w2l,
        int* __restrict__ cnt) {
    const int NX = N_NODES * 128;
    int i = blockIdx.x * 256 + threadIdx.x;
    if (i < NX) {
        float v = x[i];
        _Float16 h = (_Float16)v;
        xhi[i] = h;
        xlo[i] = (_Float16)(v - (float)h);
        return;
    }
    int j = i - NX;
    if (j < 128 * 256) { wsplit_one(W0, w0h, w0l, 128, j); return; }
    j -= 128 * 256;
    if (j < 256 * 256) { wsplit_one(W1, w1h, w1l, 256, j); return; }
    j -= 256 * 256;
    if (j < 256 * 256) { wsplit_one(W2, w2h, w2l, 256, j); return; }
    j -= 256 * 256;
    if (j < N_NODES) cnt[j] = 1;    // self-loop pre-count
}

// ---------------- MFMA GEMM (layer 0): A split hi/lo fp16, 3-term -------------
template<int K, int TERMS>
__global__ __launch_bounds__(256) void gemm16(const _Float16* __restrict__ Ahi,
        const _Float16* __restrict__ Alo,
        const _Float16* __restrict__ wt_hi, const _Float16* __restrict__ wt_lo,
        __half* __restrict__ h_half,
        const float* __restrict__ a_src, const float* __restrict__ a_dst,
        float* __restrict__ al_s, float* __restrict__ al_d, int M) {
    __shared__ _Float16 abuf[2][2][64][64];
    int tid = threadIdx.x;
    int w = tid >> 6;
    int l = tid & 63;
    int rr = l & 15;
    int kg = l >> 4;
    int row0 = blockIdx.x * 64;
    int srow = tid >> 3;
    int sgs  = tid & 7;

    f32x4 acc[4][4] = {};
    const int NT = K / 64;

    auto stage = [&](int buf, int t) {
        int k0 = t * 64;
#pragma unroll
        for (int i = 0; i < 2; ++i) {
            int row = i * 32 + srow;
            int g = sgs ^ (row & 7);
            int gr = min(row0 + row, M - 1);
            char* dst = (char*)abuf + buf * 16384 + i * 4096 + w * 1024;
            GLOAD_LDS16(&Ahi[(size_t)gr * K + k0 + g * 8], dst);
            if constexpr (TERMS == 3)
                GLOAD_LDS16(&Alo[(size_t)gr * K + k0 + g * 8], dst + 8192);
        }
    };

    stage(0, 0);
    __syncthreads();
    int cur = 0;
    for (int t = 0; t < NT; ++t) {
        if (t + 1 < NT) stage(cur ^ 1, t + 1);
        const _Float16* base_hi = &abuf[cur][0][0][0];
        const _Float16* base_lo = &abuf[cur][1][0][0];
#pragma unroll
        for (int c = 0; c < 2; ++c) {
            f16x8 ah[4], alo_[4];
#pragma unroll
            for (int fm = 0; fm < 4; ++fm) {
                int row = fm * 16 + rr;
                int gsw = ((c * 4 + kg) ^ (row & 7));
                ah[fm] = *(const f16x8*)&base_hi[row * 64 + gsw * 8];
                if constexpr (TERMS == 3)
                    alo_[fm] = *(const f16x8*)&base_lo[row * 64 + gsw * 8];
            }
            int chunk = t * 2 + c;
#pragma unroll
            for (int fn = 0; fn < 4; ++fn) {
                int col = w * 64 + fn * 16 + rr;
                size_t boff = (((size_t)chunk * 256 + col) * 4 + kg) * 8;
                f16x8 bh = *(const f16x8*)&wt_hi[boff];
                f16x8 bl = *(const f16x8*)&wt_lo[boff];
#pragma unroll
                for (int fm = 0; fm < 4; ++fm) {
                    acc[fm][fn] = __builtin_amdgcn_mfma_f32_16x16x32_f16(ah[fm], bh, acc[fm][fn], 0, 0, 0);
                    acc[fm][fn] = __builtin_amdgcn_mfma_f32_16x16x32_f16(ah[fm], bl, acc[fm][fn], 0, 0, 0);
                    if constexpr (TERMS == 3)
                        acc[fm][fn] = __builtin_amdgcn_mfma_f32_16x16x32_f16(alo_[fm], bh, acc[fm][fn], 0, 0, 0);
                }
            }
        }
        __syncthreads();
        cur ^= 1;
    }

    int head = w;
    float asv[4], adv[4];
#pragma unroll
    for (int fn = 0; fn < 4; ++fn) {
        asv[fn] = a_src[head * 64 + fn * 16 + rr];
        adv[fn] = a_dst[head * 64 + fn * 16 + rr];
    }
#pragma unroll
    for (int fm = 0; fm < 4; ++fm) {
#pragma unroll
        for (int r = 0; r < 4; ++r) {
            int row = fm * 16 + kg * 4 + r;
            int gr = row0 + row;
            float ps = acc[fm][0][r] * asv[0] + acc[fm][1][r] * asv[1]
                     + acc[fm][2][r] * asv[2] + acc[fm][3][r] * asv[3];
            float pd = acc[fm][0][r] * adv[0] + acc[fm][1][r] * adv[1]
                     + acc[fm][2][r] * adv[2] + acc[fm][3][r] * adv[3];
#pragma unroll
            for (int off = 1; off < 16; off <<= 1) {
                ps += __shfl_xor(ps, off, 64);
                pd += __shfl_xor(pd, off, 64);
            }
            if (gr < M) {
#pragma unroll
                for (int fn = 0; fn < 4; ++fn)
                    h_half[(size_t)gr * HC + w * 64 + fn * 16 + rr] = __float2half(acc[fm][fn][r]);
                if (rr == 0) {
                    al_s[gr * 4 + head] = ps;
                    al_d[gr * 4 + head] = pd;
                }
            }
        }
    }
}

// ---------------- FUSED: agg(layer l) -> LDS act tile -> gemm(layer l+1) ------
// Block owns 64 nodes. Phase A: aggregate (concat+bias+ELU, fp16) into swizzled
// LDS tile. Phase B: 2-term MFMA gemm (K=256) reading A from LDS; writes h+al.
__global__ __launch_bounds__(256) void fused_agg_gemm(
        const __half* __restrict__ hh,
        const float* __restrict__ al_s, const float* __restrict__ al_d,
        const int* __restrict__ row_ptr, const int* __restrict__ col,
        const float* __restrict__ bias,
        const _Float16* __restrict__ wt_hi, const _Float16* __restrict__ wt_lo,
        __half* __restrict__ h_out,
        const float* __restrict__ a_srcn, const float* __restrict__ a_dstn,
        float* __restrict__ al_s_out, float* __restrict__ al_d_out, int M) {
    __shared__ _Float16 a_act[64][256];      // 32KB swizzled act tile
    __shared__ int   lds_col[4][64];
    __shared__ float lds_alpha[4][64][4];
    int tid = threadIdx.x;
    int wid = tid >> 6;
    int lane = tid & 63;
    int hf = lane >> 5;
    int ln = lane & 31;
    int row0 = blockIdx.x * 64;

    // ================= phase A: aggregate 64 nodes (8 per iter) =================
    for (int it = 0; it < 8; ++it) {
        int nodeA = row0 + it * 8 + wid * 2;
        int nodeB = nodeA + 1;
        int rA = it * 8 + wid * 2, rB = rA + 1;     // LDS rows
        bool vA = nodeA < M, vB = nodeB < M;
        int sA = 0, eA = 0, sB = 0, eB = 0;
        if (vA) { sA = row_ptr[nodeA]; eA = row_ptr[nodeA + 1]; }
        if (vB) { sB = row_ptr[nodeB]; eB = row_ptr[nodeB + 1]; }
        int degA = eA - sA, degB = eB - sB;

        if (degA <= 32 && degB <= 32) {
            // ---- fast path: 2 nodes / wave ----
            int node  = hf ? nodeB : nodeA;
            int r     = hf ? rB : rA;
            int start = hf ? sB : sA;
            int deg   = hf ? degB : degA;
            bool valid = hf ? vB : vA;
            int degmax = max(degA, degB);
            float4 ald = valid ? *(const float4*)&al_d[node * 4]
                               : make_float4(0.f, 0.f, 0.f, 0.f);
            bool active = ln < deg;
            int s = active ? col[start + ln] : 0;
            float4 as = *(const float4*)&al_s[s * 4];
            float e0 = as.x + ald.x; e0 = e0 > 0.f ? e0 : SLOPE * e0;
            float e1 = as.y + ald.y; e1 = e1 > 0.f ? e1 : SLOPE * e1;
            float e2 = as.z + ald.z; e2 = e2 > 0.f ? e2 : SLOPE * e2;
            float e3 = as.w + ald.w; e3 = e3 > 0.f ? e3 : SLOPE * e3;
            float m0 = active ? e0 : -1e30f, m1 = active ? e1 : -1e30f;
            float m2 = active ? e2 : -1e30f, m3 = active ? e3 : -1e30f;
#pragma unroll
            for (int off = 1; off < 32; off <<= 1) {
                m0 = fmaxf(m0, __shfl_xor(m0, off, 64));
                m1 = fmaxf(m1, __shfl_xor(m1, off, 64));
                m2 = fmaxf(m2, __shfl_xor(m2, off, 64));
                m3 = fmaxf(m3, __shfl_xor(m3, off, 64));
            }
            float x0 = active ? expf(e0 - m0) : 0.f;
            float x1 = active ? expf(e1 - m1) : 0.f;
            float x2 = active ? expf(e2 - m2) : 0.f;
            float x3 = active ? expf(e3 - m3) : 0.f;
            float d0 = x0, d1 = x1, d2 = x2, d3 = x3;
#pragma unroll
            for (int off = 1; off < 32; off <<= 1) {
                d0 += __shfl_xor(d0, off, 64);
                d1 += __shfl_xor(d1, off, 64);
                d2 += __shfl_xor(d2, off, 64);
                d3 += __shfl_xor(d3, off, 64);
            }
            float4 a4;
            a4.x = x0 / (d0 + 1e-16f); a4.y = x1 / (d1 + 1e-16f);
            a4.z = x2 / (d2 + 1e-16f); a4.w = x3 / (d3 + 1e-16f);
            int e = hf * 32 + ln;
            lds_col[wid][e] = s;
            *(float4*)&lds_alpha[wid][e][0] = a4;
            int head = ln >> 3;
            int ch0 = ln * 8;
            float acc[8] = {0.f, 0.f, 0.f, 0.f, 0.f, 0.f, 0.f, 0.f};
            int ebase = hf * 32;
            for (int t0 = 0; t0 < degmax; t0 += 4) {
                float wv[4]; float4 raw[4];
#pragma unroll
                for (int k = 0; k < 4; ++k) {
                    int t = t0 + k;
                    int tt = max(min(t, deg - 1), 0);
                    int s2 = lds_col[wid][ebase + tt];
                    wv[k] = (t < deg) ? lds_alpha[wid][ebase + tt][head] : 0.f;
                    raw[k] = *(const float4*)&hh[(size_t)s2 * HC + ch0];
                }
#pragma unroll
                for (int k = 0; k < 4; ++k) {
                    const __half2* hp = (const __half2*)&raw[k];
                    float2 f0 = __half22float2(hp[0]);
                    float2 f1 = __half22float2(hp[1]);
                    float2 f2 = __half22float2(hp[2]);
                    float2 f3 = __half22float2(hp[3]);
                    acc[0] = fmaf(wv[k], f0.x, acc[0]); acc[1] = fmaf(wv[k], f0.y, acc[1]);
                    acc[2] = fmaf(wv[k], f1.x, acc[2]); acc[3] = fmaf(wv[k], f1.y, acc[3]);
                    acc[4] = fmaf(wv[k], f2.x, acc[4]); acc[5] = fmaf(wv[k], f2.y, acc[5]);
                    acc[6] = fmaf(wv[k], f3.x, acc[6]); acc[7] = fmaf(wv[k], f3.y, acc[7]);
                }
            }
            float b8[8];
            *(float4*)&b8[0] = *(const float4*)&bias[ch0];
            *(float4*)&b8[4] = *(const float4*)&bias[ch0 + 4];
            f16x8 v;
#pragma unroll
            for (int j = 0; j < 8; ++j) {
                float t = acc[j] + b8[j];
                t = t > 0.f ? t : expm1f(t);
                v[j] = valid ? (_Float16)t : (_Float16)0.f;
            }
            int gs = ln ^ (r & 7);                 // swizzle on WRITE
            *(f16x8*)&a_act[r][gs * 8] = v;
        } else {
            // ---- fallback: 1 node / wave ----
            for (int nn = 0; nn < 2; ++nn) {
                int node = nodeA + nn;
                int r = rA + nn;
                bool valid = node < M;
                int start = 0, end = 0;
                if (valid) { start = row_ptr[node]; end = row_ptr[node + 1]; }
                int deg = end - start;
                float4 ald = valid ? *(const float4*)&al_d[node * 4]
                                   : make_float4(0.f, 0.f, 0.f, 0.f);
                int head = lane >> 4;
                float ald_h = head == 0 ? ald.x : head == 1 ? ald.y : head == 2 ? ald.z : ald.w;
                float ax = 0.f, ay = 0.f, az = 0.f, aw = 0.f;

                if (deg <= 64) {
                    int j = start + lane;
                    bool active = lane < deg;
                    int s = active ? col[j] : 0;
                    float4 as = *(const float4*)&al_s[s * 4];
                    float e0 = as.x + ald.x; e0 = e0 > 0.f ? e0 : SLOPE * e0;
                    float e1 = as.y + ald.y; e1 = e1 > 0.f ? e1 : SLOPE * e1;
                    float e2 = as.z + ald.z; e2 = e2 > 0.f ? e2 : SLOPE * e2;
                    float e3 = as.w + ald.w; e3 = e3 > 0.f ? e3 : SLOPE * e3;
                    float m0 = active ? e0 : -1e30f, m1 = active ? e1 : -1e30f;
                    float m2 = active ? e2 : -1e30f, m3 = active ? e3 : -1e30f;
#pragma unroll
                    for (int off = 1; off < 64; off <<= 1) {
                        m0 = fmaxf(m0, __shfl_xor(m0, off, 64));
                        m1 = fmaxf(m1, __shfl_xor(m1, off, 64));
                        m2 = fmaxf(m2, __shfl_xor(m2, off, 64));
                        m3 = fmaxf(m3, __shfl_xor(m3, off, 64));
                    }
                    float x0 = active ? expf(e0 - m0) : 0.f;
                    float x1 = active ? expf(e1 - m1) : 0.f;
                    float x2 = active ? expf(e2 - m2) : 0.f;
                    float x3 = active ? expf(e3 - m3) : 0.f;
                    float d0 = x0, d1 = x1, d2 = x2, d3 = x3;
#pragma unroll
                    for (int off = 1; off < 64; off <<= 1) {
                        d0 += __shfl_xor(d0, off, 64);
                        d1 += __shfl_xor(d1, off, 64);
                        d2 += __shfl_xor(d2, off, 64);
                        d3 += __shfl_xor(d3, off, 64);
                    }
                    float4 a4;
                    a4.x = x0 / (d0 + 1e-16f); a4.y = x1 / (d1 + 1e-16f);
                    a4.z = x2 / (d2 + 1e-16f); a4.w = x3 / (d3 + 1e-16f);
                    lds_col[wid][lane] = s;
                    *(float4*)&lds_alpha[wid][lane][0] = a4;
                    for (int t0 = 0; t0 < deg; t0 += 8) {
                        int nr = deg - t0;
                        float wv[8]; float2 raw[8];
#pragma unroll
                        for (int k = 0; k < 8; ++k) {
                            if (k < nr) {
                                int s2 = lds_col[wid][t0 + k];
                                wv[k] = lds_alpha[wid][t0 + k][head];
                                raw[k] = *(const float2*)&hh[(size_t)s2 * HC + lane * 4];
                            } else {
                                wv[k] = 0.f;
                                raw[k] = make_float2(0.f, 0.f);
                            }
                        }
#pragma unroll
                        for (int k = 0; k < 8; ++k) {
                            float2 f0 = __half22float2(*(__half2*)&raw[k].x);
                            float2 f1 = __half22float2(*(__half2*)&raw[k].y);
                            ax = fmaf(wv[k], f0.x, ax); ay = fmaf(wv[k], f0.y, ay);
                            az = fmaf(wv[k], f1.x, az); aw = fmaf(wv[k], f1.y, aw);
                        }
                    }
                } else {
                    float m0 = -1e30f, m1 = -1e30f, m2 = -1e30f, m3 = -1e30f;
                    for (int j = start + lane; j < end; j += 64) {
                        int s = col[j];
                        float4 as = *(const float4*)&al_s[s * 4];
                        float e0 = as.x + ald.x; e0 = e0 > 0.f ? e0 : SLOPE * e0;
                        float e1 = as.y + ald.y; e1 = e1 > 0.f ? e1 : SLOPE * e1;
                        float e2 = as.z + ald.z; e2 = e2 > 0.f ? e2 : SLOPE * e2;
                        float e3 = as.w + ald.w; e3 = e3 > 0.f ? e3 : SLOPE * e3;
                        m0 = fmaxf(m0, e0); m1 = fmaxf(m1, e1);
                        m2 = fmaxf(m2, e2); m3 = fmaxf(m3, e3);
                    }
#pragma unroll
                    for (int off = 1; off < 64; off <<= 1) {
                        m0 = fmaxf(m0, __shfl_xor(m0, off, 64));
                        m1 = fmaxf(m1, __shfl_xor(m1, off, 64));
                        m2 = fmaxf(m2, __shfl_xor(m2, off, 64));
                        m3 = fmaxf(m3, __shfl_xor(m3, off, 64));
                    }
                    float d0 = 0.f, d1 = 0.f, d2 = 0.f, d3 = 0.f;
                    for (int j = start + lane; j < end; j += 64) {
                        int s = col[j];
                        float4 as = *(const float4*)&al_s[s * 4];
                        float e0 = as.x + ald.x; e0 = e0 > 0.f ? e0 : SLOPE * e0;
                        float e1 = as.y + ald.y; e1 = e1 > 0.f ? e1 : SLOPE * e1;
                        float e2 = as.z + ald.z; e2 = e2 > 0.f ? e2 : SLOPE * e2;
                        float e3 = as.w + ald.w; e3 = e3 > 0.f ? e3 : SLOPE * e3;
                        d0 += expf(e0 - m0); d1 += expf(e1 - m1);
                        d2 += expf(e2 - m2); d3 += expf(e3 - m3);
                    }
#pragma unroll
                    for (int off = 1; off < 64; off <<= 1) {
                        d0 += __shfl_xor(d0, off, 64);
                        d1 += __shfl_xor(d1, off, 64);
                        d2 += __shfl_xor(d2, off, 64);
                        d3 += __shfl_xor(d3, off, 64);
                    }
                    float inv0 = 1.f / (d0 + 1e-16f), inv1 = 1.f / (d1 + 1e-16f);
                    float inv2 = 1.f / (d2 + 1e-16f), inv3 = 1.f / (d3 + 1e-16f);
                    float m_h   = head == 0 ? m0   : head == 1 ? m1   : head == 2 ? m2   : m3;
                    float inv_h = head == 0 ? inv0 : head == 1 ? inv1 : head == 2 ? inv2 : inv3;
                    for (int jb = start; jb < end; jb += 64) {
                        int j = jb + lane;
                        int cs = (j < end) ? col[j] : 0;
                        int cnt2 = min(64, end - jb);
                        for (int t = 0; t < cnt2; ++t) {
                            int s = __shfl(cs, t, 64);
                            float als2 = al_s[s * 4 + head];
                            float e = als2 + ald_h; e = e > 0.f ? e : SLOPE * e;
                            float wv = expf(e - m_h) * inv_h;
                            float2 raw = *(const float2*)&hh[(size_t)s * HC + lane * 4];
                            float2 f0 = __half22float2(*(__half2*)&raw.x);
                            float2 f1 = __half22float2(*(__half2*)&raw.y);
                            ax = fmaf(wv, f0.x, ax); ay = fmaf(wv, f0.y, ay);
                            az = fmaf(wv, f1.x, az); aw = fmaf(wv, f1.y, aw);
                        }
                    }
                }
                float4 b4 = *(const float4*)&bias[lane * 4];
                float vx = ax + b4.x; vx = vx > 0.f ? vx : expm1f(vx);
                float vy = ay + b4.y; vy = vy > 0.f ? vy : expm1f(vy);
                float vz = az + b4.z; vz = vz > 0.f ? vz : expm1f(vz);
                float vw = aw + b4.w; vw = vw > 0.f ? vw : expm1f(vw);
                _Float16 v[4];
                v[0] = valid ? (_Float16)vx : (_Float16)0.f;
                v[1] = valid ? (_Float16)vy : (_Float16)0.f;
                v[2] = valid ? (_Float16)vz : (_Float16)0.f;
                v[3] = valid ? (_Float16)vw : (_Float16)0.f;
                int grp = lane >> 1, half = lane & 1;
                int gs = grp ^ (r & 7);
                *(float2*)&a_act[r][gs * 8 + half * 4] = *(float2*)v;
            }
        }
    }
    __syncthreads();

    // ================= phase B: gemm on LDS act tile (K=256, 2-term) ===========
    int w = wid;
    int rr = lane & 15;
    int kg = lane >> 4;
    f32x4 acc[4][4] = {};
#pragma unroll
    for (int ch = 0; ch < 8; ++ch) {
        f16x8 ah[4];
#pragma unroll
        for (int fm = 0; fm < 4; ++fm) {
            int row = fm * 16 + rr;
            int gsw = ((ch * 4 + kg) ^ (row & 7));   // swizzle on READ
            ah[fm] = *(const f16x8*)&a_act[row][gsw * 8];
        }
#pragma unroll
        for (int fn = 0; fn < 4; ++fn) {
            int c2 = w * 64 + fn * 16 + rr;
            size_t boff = (((size_t)ch * 256 + c2) * 4 + kg) * 8;
            f16x8 bh = *(const f16x8*)&wt_hi[boff];
            f16x8 bl = *(const f16x8*)&wt_lo[boff];
#pragma unroll
            for (int fm = 0; fm < 4; ++fm) {
                acc[fm][fn] = __builtin_amdgcn_mfma_f32_16x16x32_f16(ah[fm], bh, acc[fm][fn], 0, 0, 0);
                acc[fm][fn] = __builtin_amdgcn_mfma_f32_16x16x32_f16(ah[fm], bl, acc[fm][fn], 0, 0, 0);
            }
        }
    }

    int head = w;
    float asv[4], adv[4];
#pragma unroll
    for (int fn = 0; fn < 4; ++fn) {
        asv[fn] = a_srcn[head * 64 + fn * 16 + rr];
        adv[fn] = a_dstn[head * 64 + fn * 16 + rr];
    }
#pragma unroll
    for (int fm = 0; fm < 4; ++fm) {
#pragma unroll
        for (int r = 0; r < 4; ++r) {
            int row = fm * 16 + kg * 4 + r;
            int gr = row0 + row;
            float ps = acc[fm][0][r] * asv[0] + acc[fm][1][r] * asv[1]
                     + acc[fm][2][r] * asv[2] + acc[fm][3][r] * asv[3];
            float pd = acc[fm][0][r] * adv[0] + acc[fm][1][r] * adv[1]
                     + acc[fm][2][r] * adv[2] + acc[fm][3][r] * adv[3];
#pragma unroll
            for (int off = 1; off < 16; off <<= 1) {
                ps += __shfl_xor(ps, off, 64);
                pd += __shfl_xor(pd, off, 64);
            }
            if (gr < M) {
#pragma unroll
                for (int fn = 0; fn < 4; ++fn)
                    h_out[(size_t)gr * HC + w * 64 + fn * 16 + rr] = __float2half(acc[fm][fn][r]);
                if (rr == 0) {
                    al_s_out[gr * 4 + head] = ps;
                    al_d_out[gr * 4 + head] = pd;
                }
            }
        }
    }
}

// ---------------- CSR build ---------------------------------------------------
__global__ void hist_kernel(const int* __restrict__ dsts, int* cnt) {
    int i = blockIdx.x * blockDim.x + threadIdx.x;
    if (i < E_EDGES) atomicAdd(&cnt[dsts[i]], 1);
}
__global__ __launch_bounds__(256) void scan_bsum(const int* __restrict__ cnt,
                                                 int* __restrict__ bsum) {
    __shared__ int ws[4];
    int t = threadIdx.x;
    int i = blockIdx.x * 256 + t;
    int v = (i < N_NODES) ? cnt[i] : 0;
#pragma unroll
    for (int off = 1; off < 64; off <<= 1) v += __shfl_xor(v, off, 64);
    if ((t & 63) == 0) ws[t >> 6] = v;
    __syncthreads();
    if (t == 0) bsum[blockIdx.x] = ws[0] + ws[1] + ws[2] + ws[3];
}
__global__ __launch_bounds__(256) void scan_boff(const int* __restrict__ bsum,
                                                 int* __restrict__ boff) {
    __shared__ int s[256];
    int t = threadIdx.x;
    int v = (t < NBLK_SCAN) ? bsum[t] : 0;
    s[t] = v;
    __syncthreads();
    for (int off = 1; off < 256; off <<= 1) {
        int u = (t >= off) ? s[t - off] : 0;
        __syncthreads();
        s[t] += u;
        __syncthreads();
    }
    if (t < NBLK_SCAN) boff[t] = s[t] - v;
}
__global__ __launch_bounds__(256) void scan_final(const int* __restrict__ cnt,
        const int* __restrict__ boff, int* __restrict__ row_ptr,
        int* __restrict__ cursor) {
    __shared__ int s[256];
    int b = blockIdx.x, t = threadIdx.x;
    int i = b * 256 + t;
    int v = (i < N_NODES) ? cnt[i] : 0;
    s[t] = v;
    __syncthreads();
    for (int off = 1; off < 256; off <<= 1) {
        int u = (t >= off) ? s[t - off] : 0;
        __syncthreads();
        s[t] += u;
        __syncthreads();
    }
    int rp = boff[b] + s[t] - v;
    if (i < N_NODES) { row_ptr[i] = rp; cursor[i] = rp; }
    if (i == N_NODES - 1) row_ptr[N_NODES] = rp + v;
}
__global__ void scatter_kernel(const int* __restrict__ srcs, const int* __restrict__ dsts,
                               int* cursor, int* col) {
    int i = blockIdx.x * blockDim.x + threadIdx.x;
    if (i >= E_EDGES + N_NODES) return;
    int s, d;
    if (i < E_EDGES) { s = srcs[i]; d = dsts[i]; }
    else             { s = d = i - E_EDGES; }
    int pos = atomicAdd(&cursor[d], 1);
    col[pos] = s;
}

// ---------------- final agg (layer 2: mean heads, fp32 out) -------------------
__global__ __launch_bounds__(256) void agg_final(const __half* __restrict__ hh,
        const float* __restrict__ al_s, const float* __restrict__ al_d,
        const int* __restrict__ row_ptr, const int* __restrict__ col,
        const float* __restrict__ bias, float* __restrict__ out_f) {
    __shared__ int   lds_col[4][64];
    __shared__ float lds_alpha[4][64][4];
    int wid  = threadIdx.x >> 6;
    int lane = threadIdx.x & 63;
    int hf   = lane >> 5;
    int ln   = lane & 31;
    int nodeA = blockIdx.x * 8 + wid * 2;
    int nodeB = nodeA + 1;
    int sA = row_ptr[nodeA], eA = row_ptr[nodeA + 1];
    int sB = row_ptr[nodeB], eB = row_ptr[nodeB + 1];
    int degA = eA - sA, degB = eB - sB;

    if (degA <= 32 && degB <= 32) {
        int node  = hf ? nodeB : nodeA;
        int start = hf ? sB : sA;
        int deg   = hf ? degB : degA;
        int degmax = max(degA, degB);
        const float4 ald = *(const float4*)&al_d[node * 4];
        bool active = ln < deg;
        int s = active ? col[start + ln] : 0;
        float4 as = *(const float4*)&al_s[s * 4];
        float e0 = as.x + ald.x; e0 = e0 > 0.f ? e0 : SLOPE * e0;
        float e1 = as.y + ald.y; e1 = e1 > 0.f ? e1 : SLOPE * e1;
        float e2 = as.z + ald.z; e2 = e2 > 0.f ? e2 : SLOPE * e2;
        float e3 = as.w + ald.w; e3 = e3 > 0.f ? e3 : SLOPE * e3;
        float m0 = active ? e0 : -1e30f, m1 = active ? e1 : -1e30f;
        float m2 = active ? e2 : -1e30f, m3 = active ? e3 : -1e30f;
#pragma unroll
        for (int off = 1; off < 32; off <<= 1) {
            m0 = fmaxf(m0, __shfl_xor(m0, off, 64));
            m1 = fmaxf(m1, __shfl_xor(m1, off, 64));
            m2 = fmaxf(m2, __shfl_xor(m2, off, 64));
            m3 = fmaxf(m3, __shfl_xor(m3, off, 64));
        }
        float x0 = active ? expf(e0 - m0) : 0.f;
        float x1 = active ? expf(e1 - m1) : 0.f;
        float x2 = active ? expf(e2 - m2) : 0.f;
        float x3 = active ? expf(e3 - m3) : 0.f;
        float d0 = x0, d1 = x1, d2 = x2, d3 = x3;
#pragma unroll
        for (int off = 1; off < 32; off <<= 1) {
            d0 += __shfl_xor(d0, off, 64);
            d1 += __shfl_xor(d1, off, 64);
            d2 += __shfl_xor(d2, off, 64);
            d3 += __shfl_xor(d3, off, 64);
        }
        float4 a4;
        a4.x = x0 / (d0 + 1e-16f); a4.y = x1 / (d1 + 1e-16f);
        a4.z = x2 / (d2 + 1e-16f); a4.w = x3 / (d3 + 1e-16f);
        int e = hf * 32 + ln;
        lds_col[wid][e] = s;
        *(float4*)&lds_alpha[wid][e][0] = a4;
        int head = ln >> 3;
        int ch0 = ln * 8;
        float acc[8] = {0.f, 0.f, 0.f, 0.f, 0.f, 0.f, 0.f, 0.f};
        int ebase = hf * 32;
        for (int t0 = 0; t0 < degmax; t0 += 4) {
            float wv[4]; float4 raw[4];
#pragma unroll
            for (int k = 0; k < 4; ++k) {
                int t = t0 + k;
                int tt = max(min(t, deg - 1), 0);
                int s2 = lds_col[wid][ebase + tt];
                wv[k] = (t < deg) ? lds_alpha[wid][ebase + tt][head] : 0.f;
                raw[k] = *(const float4*)&hh[(size_t)s2 * HC + ch0];
            }
#pragma unroll
            for (int k = 0; k < 4; ++k) {
                const __half2* hp = (const __half2*)&raw[k];
                float2 f0 = __half22float2(hp[0]);
                float2 f1 = __half22float2(hp[1]);
                float2 f2 = __half22float2(hp[2]);
                float2 f3 = __half22float2(hp[3]);
                acc[0] = fmaf(wv[k], f0.x, acc[0]); acc[1] = fmaf(wv[k], f0.y, acc[1]);
                acc[2] = fmaf(wv[k], f1.x, acc[2]); acc[3] = fmaf(wv[k], f1.y, acc[3]);
                acc[4] = fmaf(wv[k], f2.x, acc[4]); acc[5] = fmaf(wv[k], f2.y, acc[5]);
                acc[6] = fmaf(wv[k], f3.x, acc[6]); acc[7] = fmaf(wv[k], f3.y, acc[7]);
            }
        }
#pragma unroll
        for (int j = 0; j < 8; ++j) {
            acc[j] += __shfl_xor(acc[j], 8, 64);
            acc[j] += __shfl_xor(acc[j], 16, 64);
        }
        if (ln < 8) {
            float v[8];
#pragma unroll
            for (int j = 0; j < 8; ++j)
                v[j] = acc[j] * 0.25f + bias[ln * 8 + j];
            *(float4*)&out_f[(size_t)node * 64 + ln * 8]     = *(float4*)&v[0];
            *(float4*)&out_f[(size_t)node * 64 + ln * 8 + 4] = *(float4*)&v[4];
        }
        return;
    }

    for (int nn = 0; nn < 2; ++nn) {
        int node = nodeA + nn;
        int start = row_ptr[node], end = row_ptr[node + 1];
        int deg = end - start;
        const float4 ald = *(const float4*)&al_d[node * 4];
        int head = lane >> 4;
        float ald_h = head == 0 ? ald.x : head == 1 ? ald.y : head == 2 ? ald.z : ald.w;
        float ax = 0.f, ay = 0.f, az = 0.f, aw = 0.f;
        if (deg <= 64) {
            int j = start + lane;
            bool active = j < end;
            int s = active ? col[j] : 0;
            float4 as = *(const float4*)&al_s[s * 4];
            float e0 = as.x + ald.x; e0 = e0 > 0.f ? e0 : SLOPE * e0;
            float e1 = as.y + ald.y; e1 = e1 > 0.f ? e1 : SLOPE * e1;
            float e2 = as.z + ald.z; e2 = e2 > 0.f ? e2 : SLOPE * e2;
            float e3 = as.w + ald.w; e3 = e3 > 0.f ? e3 : SLOPE * e3;
            float m0 = active ? e0 : -1e30f, m1 = active ? e1 : -1e30f;
            float m2 = active ? e2 : -1e30f, m3 = active ? e3 : -1e30f;
#pragma unroll
            for (int off = 1; off < 64; off <<= 1) {
                m0 = fmaxf(m0, __shfl_xor(m0, off, 64));
                m1 = fmaxf(m1, __shfl_xor(m1, off, 64));
                m2 = fmaxf(m2, __shfl_xor(m2, off, 64));
                m3 = fmaxf(m3, __shfl_xor(m3, off, 64));
            }
            float x0 = active ? expf(e0 - m0) : 0.f;
            float x1 = active ? expf(e1 - m1) : 0.f;
            float x2 = active ? expf(e2 - m2) : 0.f;
            float x3 = active ? expf(e3 - m3) : 0.f;
            float d0 = x0, d1 = x1, d2 = x2, d3 = x3;
#pragma unroll
            for (int off = 1; off < 64; off <<= 1) {
                d0 += __shfl_xor(d0, off, 64);
                d1 += __shfl_xor(d1, off, 64);
                d2 += __shfl_xor(d2, off, 64);
                d3 += __shfl_xor(d3, off, 64);
            }
            float4 a4;
            a4.x = x0 / (d0 + 1e-16f); a4.y = x1 / (d1 + 1e-16f);
            a4.z = x2 / (d2 + 1e-16f); a4.w = x3 / (d3 + 1e-16f);
            lds_col[wid][lane] = s;
            *(float4*)&lds_alpha[wid][lane][0] = a4;
            for (int t0 = 0; t0 < deg; t0 += 8) {
                int nr = deg - t0;
                float wv[8]; float2 raw[8];
#pragma unroll
                for (int k = 0; k < 8; ++k) {
                    if (k < nr) {
                        int s2 = lds_col[wid][t0 + k];
                        wv[k] = lds_alpha[wid][t0 + k][head];
                        raw[k] = *(const float2*)&hh[(size_t)s2 * HC + lane * 4];
                    } else {
                        wv[k] = 0.f;
                        raw[k] = make_float2(0.f, 0.f);
                    }
                }
#pragma unroll
                for (int k = 0; k < 8; ++k) {
                    float2 f0 = __half22float2(*(__half2*)&raw[k].x);
                    float2 f1 = __half22float2(*(__half2*)&raw[k].y);
                    ax = fmaf(wv[k], f0.x, ax); ay = fmaf(wv[k], f0.y, ay);
                    az = fmaf(wv[k], f1.x, az); aw = fmaf(wv[k], f1.y, aw);
                }
            }
        } else {
            float m0 = -1e30f, m1 = -1e30f, m2 = -1e30f, m3 = -1e30f;
            for (int j = start + lane; j < end; j += 64) {
                int s = col[j];
                float4 as = *(const float4*)&al_s[s * 4];
                float e0 = as.x + ald.x; e0 = e0 > 0.f ? e0 : SLOPE * e0;
                float e1 = as.y + ald.y; e1 = e1 > 0.f ? e1 : SLOPE * e1;
                float e2 = as.z + ald.z; e2 = e2 > 0.f ? e2 : SLOPE * e2;
                float e3 = as.w + ald.w; e3 = e3 > 0.f ? e3 : SLOPE * e3;
                m0 = fmaxf(m0, e0); m1 = fmaxf(m1, e1);
                m2 = fmaxf(m2, e2); m3 = fmaxf(m3, e3);
            }
#pragma unroll
            for (int off = 1; off < 64; off <<= 1) {
                m0 = fmaxf(m0, __shfl_xor(m0, off, 64));
                m1 = fmaxf(m1, __shfl_xor(m1, off, 64));
                m2 = fmaxf(m2, __shfl_xor(m2, off, 64));
                m3 = fmaxf(m3, __shfl_xor(m3, off, 64));
            }
            float d0 = 0.f, d1 = 0.f, d2 = 0.f, d3 = 0.f;
            for (int j = start + lane; j < end; j += 64) {
                int s = col[j];
                float4 as = *(const float4*)&al_s[s * 4];
                float e0 = as.x + ald.x; e0 = e0 > 0.f ? e0 : SLOPE * e0;
                float e1 = as.y + ald.y; e1 = e1 > 0.f ? e1 : SLOPE * e1;
                float e2 = as.z + ald.z; e2 = e2 > 0.f ? e2 : SLOPE * e2;
                float e3 = as.w + ald.w; e3 = e3 > 0.f ? e3 : SLOPE * e3;
                d0 += expf(e0 - m0); d1 += expf(e1 - m1);
                d2 += expf(e2 - m2); d3 += expf(e3 - m3);
            }
#pragma unroll
            for (int off = 1; off < 64; off <<= 1) {
                d0 += __shfl_xor(d0, off, 64);
                d1 += __shfl_xor(d1, off, 64);
                d2 += __shfl_xor(d2, off, 64);
                d3 += __shfl_xor(d3, off, 64);
            }
            float inv0 = 1.f / (d0 + 1e-16f), inv1 = 1.f / (d1 + 1e-16f);
            float inv2 = 1.f / (d2 + 1e-16f), inv3 = 1.f / (d3 + 1e-16f);
            float m_h   = head == 0 ? m0   : head == 1 ? m1   : head == 2 ? m2   : m3;
            float inv_h = head == 0 ? inv0 : head == 1 ? inv1 : head == 2 ? inv2 : inv3;
            for (int jb = start; jb < end; jb += 64) {
                int j = jb + lane;
                int cs = (j < end) ? col[j] : 0;
                int cnt2 = min(64, end - jb);
                for (int t = 0; t < cnt2; ++t) {
                    int s = __shfl(cs, t, 64);
                    float als2 = al_s[s * 4 + head];
                    float e = als2 + ald_h; e = e > 0.f ? e : SLOPE * e;
                    float wv = expf(e - m_h) * inv_h;
                    float2 raw = *(const float2*)&hh[(size_t)s * HC + lane * 4];
                    float2 f0 = __half22float2(*(__half2*)&raw.x);
                    float2 f1 = __half22float2(*(__half2*)&raw.y);
                    ax = fmaf(wv, f0.x, ax); ay = fmaf(wv, f0.y, ay);
                    az = fmaf(wv, f1.x, az); aw = fmaf(wv, f1.y, aw);
                }
            }
        }
#pragma unroll
        for (int off = 16; off < 64; off <<= 1) {
            ax += __shfl_xor(ax, off, 64);
            ay += __shfl_xor(ay, off, 64);
            az += __shfl_xor(az, off, 64);
            aw += __shfl_xor(aw, off, 64);
        }
        if (lane < 16) {
            float4 b4 = *(const float4*)&bias[lane * 4];
            float4 v = make_float4(ax * 0.25f + b4.x, ay * 0.25f + b4.y,
                                   az * 0.25f + b4.z, aw * 0.25f + b4.w);
            *(float4*)&out_f[(size_t)node * 64 + lane * 4] = v;
        }
    }
}

// ---------------- fused pool + MLP --------------------------------------------
__global__ __launch_bounds__(1024) void poolmlp_kernel(const float* __restrict__ act,
        const int* __restrict__ batch,
        const float* __restrict__ pW1, const float* __restrict__ pb1,
        const float* __restrict__ pW2, const float* __restrict__ pb2,
        float* __restrict__ outp) {
    __shared__ float part[16][64];
    __shared__ float p[64];
    __shared__ float z[32];
    int b = blockIdx.x;
    int warp = threadIdx.x >> 6;
    int lane = threadIdx.x & 63;
    int lo = 0, hi = N_NODES;
    while (lo < hi) { int mid = (lo + hi) >> 1; if (batch[mid] < b) lo = mid + 1; else hi = mid; }
    int s = lo;
    lo = 0; hi = N_NODES;
    while (lo < hi) { int mid = (lo + hi) >> 1; if (batch[mid] < b + 1) lo = mid + 1; else hi = mid; }
    int e = lo;
    float sum = 0.f;
    for (int n = s + warp; n < e; n += 16)
        sum += act[(size_t)n * 64 + lane];
    part[warp][lane] = sum;
    __syncthreads();
    int t = threadIdx.x;
    if (t < 64) {
        float tt = 0.f;
#pragma unroll
        for (int r = 0; r < 16; ++r) tt += part[r][t];
        p[t] = tt / (float)max(e - s, 1);
    }
    __syncthreads();
    if (t < 32) {
        float s2 = pb1[t];
        for (int c = 0; c < 64; ++c) s2 += p[c] * pW1[c * 32 + t];
        z[t] = s2 > 0.f ? s2 : 0.f;
    }
    __syncthreads();
    if (t < OUT_DIM) {
        float s2 = pb2[t];
        for (int k = 0; k < 32; ++k) s2 += z[k] * pW2[k * 10 + t];
        outp[b * 10 + t] = s2;
    }
}

// ---------------- launch ------------------------------------------------------
extern "C" void kernel_launch(void* const* d_in, const int* in_sizes, int n_in,
                              void* d_out, int out_size, void* d_ws, size_t ws_size,
                              hipStream_t stream) {
    const float* x    = (const float*)d_in[0];
    const int*   ei   = (const int*)d_in[1];
    const int*   batch= (const int*)d_in[2];
    const float* W0   = (const float*)d_in[3];
    const float* b0   = (const float*)d_in[4];
    const float* as0  = (const float*)d_in[5];
    const float* ad0  = (const float*)d_in[6];
    const float* W1   = (const float*)d_in[7];
    const float* b1   = (const float*)d_in[8];
    const float* as1  = (const float*)d_in[9];
    const float* ad1  = (const float*)d_in[10];
    const float* W2   = (const float*)d_in[11];
    const float* b2   = (const float*)d_in[12];
    const float* as2  = (const float*)d_in[13];
    const float* ad2  = (const float*)d_in[14];
    const float* pW1  = (const float*)d_in[15];
    const float* pb1  = (const float*)d_in[16];
    const float* pW2  = (const float*)d_in[17];
    const float* pb2  = (const float*)d_in[18];
    float* out = (float*)d_out;

    char* ws = (char*)d_ws;
    size_t off = 0;
    auto alloc = [&](size_t bytes) -> void* {
        void* p = ws + off;
        off += (bytes + 255) & ~(size_t)255;
        return p;
    };
    __half*    h_a    = (__half*)alloc((size_t)N_NODES * HC * 2);
    __half*    h_b    = (__half*)alloc((size_t)N_NODES * HC * 2);
    float*     act_f  = (float*)alloc((size_t)N_NODES * 64 * 4);
    _Float16*  xhi    = (_Float16*)alloc((size_t)N_NODES * 128 * 2);
    _Float16*  xlo    = (_Float16*)alloc((size_t)N_NODES * 128 * 2);
    float* als_a  = (float*)alloc((size_t)N_NODES * 4 * 4);
    float* ald_a  = (float*)alloc((size_t)N_NODES * 4 * 4);
    float* als_b  = (float*)alloc((size_t)N_NODES * 4 * 4);
    float* ald_b  = (float*)alloc((size_t)N_NODES * 4 * 4);
    int*   cnt    = (int*)alloc((size_t)N_NODES * 4);
    int*   row_ptr= (int*)alloc((size_t)(N_NODES + 1) * 4);
    int*   cursor = (int*)alloc((size_t)N_NODES * 4);
    int*   col    = (int*)alloc((size_t)(E_EDGES + N_NODES) * 4);
    int*   bsum   = (int*)alloc((size_t)NBLK_SCAN * 4);
    int*   boff   = (int*)alloc((size_t)NBLK_SCAN * 4);
    _Float16* w0h = (_Float16*)alloc((size_t)128 * 256 * 2);
    _Float16* w0l = (_Float16*)alloc((size_t)128 * 256 * 2);
    _Float16* w1h = (_Float16*)alloc((size_t)256 * 256 * 2);
    _Float16* w1l = (_Float16*)alloc((size_t)256 * 256 * 2);
    _Float16* w2h = (_Float16*)alloc((size_t)256 * 256 * 2);
    _Float16* w2l = (_Float16*)alloc((size_t)256 * 256 * 2);

    const int* srcs = ei;
    const int* dsts = ei + E_EDGES;

    // fused prep: x split + 3 W splits + cnt=1 init
    const int PREP_N = N_NODES * 128 + 128 * 256 + 256 * 256 + 256 * 256 + N_NODES;
    prep_split<<<(PREP_N + 255) / 256, 256, 0, stream>>>(
        x, xhi, xlo, W0, w0h, w0l, W1, w1h, w1l, W2, w2h, w2l, cnt);

    // CSR by dst
    hist_kernel<<<(E_EDGES + 255) / 256, 256, 0, stream>>>(dsts, cnt);
    scan_bsum<<<NBLK_SCAN, 256, 0, stream>>>(cnt, bsum);
    scan_boff<<<1, 256, 0, stream>>>(bsum, boff);
    scan_final<<<NBLK_SCAN, 256, 0, stream>>>(cnt, boff, row_ptr, cursor);
    scatter_kernel<<<(E_EDGES + N_NODES + 255) / 256, 256, 0, stream>>>(srcs, dsts, cursor, col);

    int gblk = (N_NODES + 63) / 64;   // 782
    int nblk = (N_NODES + 7) / 8;     // 6250

    // layer 0 gemm: x(hi/lo) * W0 -> h_a, al_a
    gemm16<128, 3><<<gblk, 256, 0, stream>>>(xhi, xlo, w0h, w0l, h_a, as0, ad0, als_a, ald_a, N_NODES);
    // fused: agg0(h_a) -> act LDS -> gemm1 -> h_b, al_b
    fused_agg_gemm<<<gblk, 256, 0, stream>>>(h_a, als_a, ald_a, row_ptr, col, b0,
                                             w1h, w1l, h_b, as1, ad1, als_b, ald_b, N_NODES);
    // fused: agg1(h_b) -> act LDS -> gemm2 -> h_a, al_a
    fused_agg_gemm<<<gblk, 256, 0, stream>>>(h_b, als_b, ald_b, row_ptr, col, b1,
                                             w2h, w2l, h_a, as2, ad2, als_a, ald_a, N_NODES);
    // final agg (mean heads) -> act_f
    agg_final<<<nblk, 256, 0, stream>>>(h_a, als_a, ald_a, row_ptr, col, b2, act_f);

    poolmlp_kernel<<<B_GR, 1024, 0, stream>>>(act_f, batch, pW1, pb1, pW2, pb2, out);
}

// Round 11
// 430.792 us; speedup vs baseline: 1.1075x; 1.1075x over previous
//
#include <hip/hip_runtime.h>
#include <hip/hip_fp16.h>
#include <cstdint>

#define N_NODES 50000
#define E_EDGES 800000
#define HC 256           // H*C
#define B_GR 64
#define OUT_DIM 10
#define SLOPE 0.2f
#define NBLK_SCAN ((N_NODES + 255) / 256)   // 196

using f16x8 = __attribute__((ext_vector_type(8))) _Float16;
using f32x4 = __attribute__((ext_vector_type(4))) float;

#define GLOAD_LDS16(gsrc, ldst) \
    __builtin_amdgcn_global_load_lds((const __attribute__((address_space(1))) void*)(gsrc), \
        (__attribute__((address_space(3))) void*)(ldst), 16, 0, 0)

// ---------------- prep: x->hi/lo; W0/1/2 -> fragment-major hi/lo; cnt=1 -------
__device__ inline void wsplit_one(const float* W, _Float16* wh, _Float16* wl,
                                  int K, int i) {
    int k = i >> 8, n = i & 255;
    float v = W[i];
    _Float16 h = (_Float16)v;
    _Float16 l = (_Float16)(v - (float)h);
    int oidx = ((((k >> 5) * 256 + n) * 4) + ((k >> 3) & 3)) * 8 + (k & 7);
    wh[oidx] = h;
    wl[oidx] = l;
}

__global__ void prep_split(const float* __restrict__ x,
        _Float16* __restrict__ xhi, _Float16* __restrict__ xlo,
        const float* __restrict__ W0, _Float16* __restrict__ w0h, _Float16* __restrict__ w0l,
        const float* __restrict__ W1, _Float16* __restrict__ w1h, _Float16* __restrict__ w1l,
        const float* __restrict__ W2, _Float16* __restrict__ w2h, _Float16* __restrict__ w2l,
        int* __restrict__ cnt) {
    const int NX = N_NODES * 128;
    int i = blockIdx.x * 256 + threadIdx.x;
    if (i < NX) {
        float v = x[i];
        _Float16 h = (_Float16)v;
        xhi[i] = h;
        xlo[i] = (_Float16)(v - (float)h);
        return;
    }
    int j = i - NX;
    if (j < 128 * 256) { wsplit_one(W0, w0h, w0l, 128, j); return; }
    j -= 128 * 256;
    if (j < 256 * 256) { wsplit_one(W1, w1h, w1l, 256, j); return; }
    j -= 256 * 256;
    if (j < 256 * 256) { wsplit_one(W2, w2h, w2l, 256, j); return; }
    j -= 256 * 256;
    if (j < N_NODES) cnt[j] = 1;    // self-loop pre-count
}

// ---------------- MFMA GEMM: A split hi/lo fp16 (3-term) or exact (2-term) ----
template<int K, int TERMS>
__global__ __launch_bounds__(256) void gemm16(const _Float16* __restrict__ Ahi,
        const _Float16* __restrict__ Alo,
        const _Float16* __restrict__ wt_hi, const _Float16* __restrict__ wt_lo,
        __half* __restrict__ h_half,
        const float* __restrict__ a_src, const float* __restrict__ a_dst,
        float* __restrict__ al_s, float* __restrict__ al_d, int M) {
    __shared__ _Float16 abuf[2][2][64][64];
    int tid = threadIdx.x;
    int w = tid >> 6;
    int l = tid & 63;
    int rr = l & 15;
    int kg = l >> 4;
    int row0 = blockIdx.x * 64;
    int srow = tid >> 3;
    int sgs  = tid & 7;

    f32x4 acc[4][4] = {};
    const int NT = K / 64;

    auto stage = [&](int buf, int t) {
        int k0 = t * 64;
#pragma unroll
        for (int i = 0; i < 2; ++i) {
            int row = i * 32 + srow;
            int g = sgs ^ (row & 7);
            int gr = min(row0 + row, M - 1);
            char* dst = (char*)abuf + buf * 16384 + i * 4096 + w * 1024;
            GLOAD_LDS16(&Ahi[(size_t)gr * K + k0 + g * 8], dst);
            if constexpr (TERMS == 3)
                GLOAD_LDS16(&Alo[(size_t)gr * K + k0 + g * 8], dst + 8192);
        }
    };

    stage(0, 0);
    __syncthreads();
    int cur = 0;
    for (int t = 0; t < NT; ++t) {
        if (t + 1 < NT) stage(cur ^ 1, t + 1);
        const _Float16* base_hi = &abuf[cur][0][0][0];
        const _Float16* base_lo = &abuf[cur][1][0][0];
#pragma unroll
        for (int c = 0; c < 2; ++c) {
            f16x8 ah[4], alo_[4];
#pragma unroll
            for (int fm = 0; fm < 4; ++fm) {
                int row = fm * 16 + rr;
                int gsw = ((c * 4 + kg) ^ (row & 7));
                ah[fm] = *(const f16x8*)&base_hi[row * 64 + gsw * 8];
                if constexpr (TERMS == 3)
                    alo_[fm] = *(const f16x8*)&base_lo[row * 64 + gsw * 8];
            }
            int chunk = t * 2 + c;
#pragma unroll
            for (int fn = 0; fn < 4; ++fn) {
                int col = w * 64 + fn * 16 + rr;
                size_t boff = (((size_t)chunk * 256 + col) * 4 + kg) * 8;
                f16x8 bh = *(const f16x8*)&wt_hi[boff];
                f16x8 bl = *(const f16x8*)&wt_lo[boff];
#pragma unroll
                for (int fm = 0; fm < 4; ++fm) {
                    acc[fm][fn] = __builtin_amdgcn_mfma_f32_16x16x32_f16(ah[fm], bh, acc[fm][fn], 0, 0, 0);
                    acc[fm][fn] = __builtin_amdgcn_mfma_f32_16x16x32_f16(ah[fm], bl, acc[fm][fn], 0, 0, 0);
                    if constexpr (TERMS == 3)
                        acc[fm][fn] = __builtin_amdgcn_mfma_f32_16x16x32_f16(alo_[fm], bh, acc[fm][fn], 0, 0, 0);
                }
            }
        }
        __syncthreads();
        cur ^= 1;
    }

    int head = w;
    float asv[4], adv[4];
#pragma unroll
    for (int fn = 0; fn < 4; ++fn) {
        asv[fn] = a_src[head * 64 + fn * 16 + rr];
        adv[fn] = a_dst[head * 64 + fn * 16 + rr];
    }
#pragma unroll
    for (int fm = 0; fm < 4; ++fm) {
#pragma unroll
        for (int r = 0; r < 4; ++r) {
            int row = fm * 16 + kg * 4 + r;
            int gr = row0 + row;
            float ps = acc[fm][0][r] * asv[0] + acc[fm][1][r] * asv[1]
                     + acc[fm][2][r] * asv[2] + acc[fm][3][r] * asv[3];
            float pd = acc[fm][0][r] * adv[0] + acc[fm][1][r] * adv[1]
                     + acc[fm][2][r] * adv[2] + acc[fm][3][r] * adv[3];
#pragma unroll
            for (int off = 1; off < 16; off <<= 1) {
                ps += __shfl_xor(ps, off, 64);
                pd += __shfl_xor(pd, off, 64);
            }
            if (gr < M) {
#pragma unroll
                for (int fn = 0; fn < 4; ++fn)
                    h_half[(size_t)gr * HC + w * 64 + fn * 16 + rr] = __float2half(acc[fm][fn][r]);
                if (rr == 0) {
                    al_s[gr * 4 + head] = ps;
                    al_d[gr * 4 + head] = pd;
                }
            }
        }
    }
}

// ---------------- CSR build ---------------------------------------------------
__global__ void hist_kernel(const int* __restrict__ dsts, int* cnt) {
    int i = blockIdx.x * blockDim.x + threadIdx.x;
    if (i < E_EDGES) atomicAdd(&cnt[dsts[i]], 1);
}
__global__ __launch_bounds__(256) void scan_bsum(const int* __restrict__ cnt,
                                                 int* __restrict__ bsum) {
    __shared__ int ws[4];
    int t = threadIdx.x;
    int i = blockIdx.x * 256 + t;
    int v = (i < N_NODES) ? cnt[i] : 0;
#pragma unroll
    for (int off = 1; off < 64; off <<= 1) v += __shfl_xor(v, off, 64);
    if ((t & 63) == 0) ws[t >> 6] = v;
    __syncthreads();
    if (t == 0) bsum[blockIdx.x] = ws[0] + ws[1] + ws[2] + ws[3];
}
__global__ __launch_bounds__(256) void scan_boff(const int* __restrict__ bsum,
                                                 int* __restrict__ boff) {
    __shared__ int s[256];
    int t = threadIdx.x;
    int v = (t < NBLK_SCAN) ? bsum[t] : 0;
    s[t] = v;
    __syncthreads();
    for (int off = 1; off < 256; off <<= 1) {
        int u = (t >= off) ? s[t - off] : 0;
        __syncthreads();
        s[t] += u;
        __syncthreads();
    }
    if (t < NBLK_SCAN) boff[t] = s[t] - v;
}
__global__ __launch_bounds__(256) void scan_final(const int* __restrict__ cnt,
        const int* __restrict__ boff, int* __restrict__ row_ptr,
        int* __restrict__ cursor) {
    __shared__ int s[256];
    int b = blockIdx.x, t = threadIdx.x;
    int i = b * 256 + t;
    int v = (i < N_NODES) ? cnt[i] : 0;
    s[t] = v;
    __syncthreads();
    for (int off = 1; off < 256; off <<= 1) {
        int u = (t >= off) ? s[t - off] : 0;
        __syncthreads();
        s[t] += u;
        __syncthreads();
    }
    int rp = boff[b] + s[t] - v;
    if (i < N_NODES) { row_ptr[i] = rp; cursor[i] = rp; }
    if (i == N_NODES - 1) row_ptr[N_NODES] = rp + v;
}
__global__ void scatter_kernel(const int* __restrict__ srcs, const int* __restrict__ dsts,
                               int* cursor, int* col) {
    int i = blockIdx.x * blockDim.x + threadIdx.x;
    if (i >= E_EDGES + N_NODES) return;
    int s, d;
    if (i < E_EDGES) { s = srcs[i]; d = dsts[i]; }
    else             { s = d = i - E_EDGES; }
    int pos = atomicAdd(&cursor[d], 1);
    col[pos] = s;
}

// ---------------- per-node softmax + aggregation -----------------------------
// mode 0: concat heads, +bias[256], ELU, fp16 out (act_h).
// mode 1: mean heads, +bias[64], no ELU, fp32 out (act_f).
// Fast path: 2 nodes/wave, 8-deep pipelined gather.
__global__ __launch_bounds__(256) void agg_kernel(const __half* __restrict__ hh,
        const float* __restrict__ al_s, const float* __restrict__ al_d,
        const int* __restrict__ row_ptr, const int* __restrict__ col,
        const float* __restrict__ bias, _Float16* __restrict__ out_h,
        float* __restrict__ out_f, int mode) {
    __shared__ int   lds_col[4][64];
    __shared__ float lds_alpha[4][64][4];
    int wid  = threadIdx.x >> 6;
    int lane = threadIdx.x & 63;
    int hf   = lane >> 5;
    int ln   = lane & 31;
    int nodeA = blockIdx.x * 8 + wid * 2;   // N_NODES % 8 == 0 -> no tail
    int nodeB = nodeA + 1;
    int sA = row_ptr[nodeA], eA = row_ptr[nodeA + 1];
    int sB = row_ptr[nodeB], eB = row_ptr[nodeB + 1];
    int degA = eA - sA, degB = eB - sB;

    if (degA <= 32 && degB <= 32) {
        // ================= fast path: 2 nodes / wave =================
        int node  = hf ? nodeB : nodeA;
        int start = hf ? sB : sA;
        int deg   = hf ? degB : degA;
        int degmax = max(degA, degB);
        const float4 ald = *(const float4*)&al_d[node * 4];
        bool active = ln < deg;
        int s = active ? col[start + ln] : 0;
        float4 as = *(const float4*)&al_s[s * 4];
        float e0 = as.x + ald.x; e0 = e0 > 0.f ? e0 : SLOPE * e0;
        float e1 = as.y + ald.y; e1 = e1 > 0.f ? e1 : SLOPE * e1;
        float e2 = as.z + ald.z; e2 = e2 > 0.f ? e2 : SLOPE * e2;
        float e3 = as.w + ald.w; e3 = e3 > 0.f ? e3 : SLOPE * e3;
        float m0 = active ? e0 : -1e30f, m1 = active ? e1 : -1e30f;
        float m2 = active ? e2 : -1e30f, m3 = active ? e3 : -1e30f;
#pragma unroll
        for (int off = 1; off < 32; off <<= 1) {
            m0 = fmaxf(m0, __shfl_xor(m0, off, 64));
            m1 = fmaxf(m1, __shfl_xor(m1, off, 64));
            m2 = fmaxf(m2, __shfl_xor(m2, off, 64));
            m3 = fmaxf(m3, __shfl_xor(m3, off, 64));
        }
        float x0 = active ? expf(e0 - m0) : 0.f;
        float x1 = active ? expf(e1 - m1) : 0.f;
        float x2 = active ? expf(e2 - m2) : 0.f;
        float x3 = active ? expf(e3 - m3) : 0.f;
        float d0 = x0, d1 = x1, d2 = x2, d3 = x3;
#pragma unroll
        for (int off = 1; off < 32; off <<= 1) {
            d0 += __shfl_xor(d0, off, 64);
            d1 += __shfl_xor(d1, off, 64);
            d2 += __shfl_xor(d2, off, 64);
            d3 += __shfl_xor(d3, off, 64);
        }
        float4 a4;
        a4.x = x0 / (d0 + 1e-16f); a4.y = x1 / (d1 + 1e-16f);
        a4.z = x2 / (d2 + 1e-16f); a4.w = x3 / (d3 + 1e-16f);
        int e = hf * 32 + ln;
        lds_col[wid][e] = s;
        *(float4*)&lds_alpha[wid][e][0] = a4;
        int head = ln >> 3;
        int ch0 = ln * 8;
        float acc[8] = {0.f, 0.f, 0.f, 0.f, 0.f, 0.f, 0.f, 0.f};
        int ebase = hf * 32;
        for (int t0 = 0; t0 < degmax; t0 += 8) {
            float wv[8]; float4 raw[8];
#pragma unroll
            for (int k = 0; k < 8; ++k) {
                int t = t0 + k;
                int tt = min(t, deg - 1);          // deg >= 1 (self-loop)
                int s2 = lds_col[wid][ebase + tt];
                wv[k] = (t < deg) ? lds_alpha[wid][ebase + tt][head] : 0.f;
                raw[k] = *(const float4*)&hh[(size_t)s2 * HC + ch0];
            }
#pragma unroll
            for (int k = 0; k < 8; ++k) {
                const __half2* hp = (const __half2*)&raw[k];
                float2 f0 = __half22float2(hp[0]);
                float2 f1 = __half22float2(hp[1]);
                float2 f2 = __half22float2(hp[2]);
                float2 f3 = __half22float2(hp[3]);
                acc[0] = fmaf(wv[k], f0.x, acc[0]); acc[1] = fmaf(wv[k], f0.y, acc[1]);
                acc[2] = fmaf(wv[k], f1.x, acc[2]); acc[3] = fmaf(wv[k], f1.y, acc[3]);
                acc[4] = fmaf(wv[k], f2.x, acc[4]); acc[5] = fmaf(wv[k], f2.y, acc[5]);
                acc[6] = fmaf(wv[k], f3.x, acc[6]); acc[7] = fmaf(wv[k], f3.y, acc[7]);
            }
        }
        if (mode == 0) {
            float b8[8];
            *(float4*)&b8[0] = *(const float4*)&bias[ch0];
            *(float4*)&b8[4] = *(const float4*)&bias[ch0 + 4];
            _Float16 v[8];
#pragma unroll
            for (int j = 0; j < 8; ++j) {
                float t = acc[j] + b8[j];
                v[j] = (_Float16)(t > 0.f ? t : expm1f(t));
            }
            *(float4*)&out_h[(size_t)node * HC + ch0] = *(float4*)v;   // 16B
        } else {
#pragma unroll
            for (int j = 0; j < 8; ++j) {
                acc[j] += __shfl_xor(acc[j], 8, 64);
                acc[j] += __shfl_xor(acc[j], 16, 64);
            }
            if (ln < 8) {
                float v[8];
#pragma unroll
                for (int j = 0; j < 8; ++j)
                    v[j] = acc[j] * 0.25f + bias[ln * 8 + j];
                *(float4*)&out_f[(size_t)node * 64 + ln * 8]     = *(float4*)&v[0];
                *(float4*)&out_f[(size_t)node * 64 + ln * 8 + 4] = *(float4*)&v[4];
            }
        }
        return;
    }

    // ================= fallback: 1 node / wave (rare, deg>32) =================
    for (int nn = 0; nn < 2; ++nn) {
        int node = nodeA + nn;
        int start = row_ptr[node], end = row_ptr[node + 1];
        int deg = end - start;
        const float4 ald = *(const float4*)&al_d[node * 4];
        int head = lane >> 4;
        float ald_h = head == 0 ? ald.x : head == 1 ? ald.y : head == 2 ? ald.z : ald.w;
        float ax = 0.f, ay = 0.f, az = 0.f, aw = 0.f;

        if (deg <= 64) {
            int j = start + lane;
            bool active = j < end;
            int s = active ? col[j] : 0;
            float4 as = *(const float4*)&al_s[s * 4];
            float e0 = as.x + ald.x; e0 = e0 > 0.f ? e0 : SLOPE * e0;
            float e1 = as.y + ald.y; e1 = e1 > 0.f ? e1 : SLOPE * e1;
            float e2 = as.z + ald.z; e2 = e2 > 0.f ? e2 : SLOPE * e2;
            float e3 = as.w + ald.w; e3 = e3 > 0.f ? e3 : SLOPE * e3;
            float m0 = active ? e0 : -1e30f, m1 = active ? e1 : -1e30f;
            float m2 = active ? e2 : -1e30f, m3 = active ? e3 : -1e30f;
#pragma unroll
            for (int off = 1; off < 64; off <<= 1) {
                m0 = fmaxf(m0, __shfl_xor(m0, off, 64));
                m1 = fmaxf(m1, __shfl_xor(m1, off, 64));
                m2 = fmaxf(m2, __shfl_xor(m2, off, 64));
                m3 = fmaxf(m3, __shfl_xor(m3, off, 64));
            }
            float x0 = active ? expf(e0 - m0) : 0.f;
            float x1 = active ? expf(e1 - m1) : 0.f;
            float x2 = active ? expf(e2 - m2) : 0.f;
            float x3 = active ? expf(e3 - m3) : 0.f;
            float d0 = x0, d1 = x1, d2 = x2, d3 = x3;
#pragma unroll
            for (int off = 1; off < 64; off <<= 1) {
                d0 += __shfl_xor(d0, off, 64);
                d1 += __shfl_xor(d1, off, 64);
                d2 += __shfl_xor(d2, off, 64);
                d3 += __shfl_xor(d3, off, 64);
            }
            float4 a4;
            a4.x = x0 / (d0 + 1e-16f); a4.y = x1 / (d1 + 1e-16f);
            a4.z = x2 / (d2 + 1e-16f); a4.w = x3 / (d3 + 1e-16f);
            lds_col[wid][lane] = s;
            *(float4*)&lds_alpha[wid][lane][0] = a4;
            for (int t0 = 0; t0 < deg; t0 += 8) {
                int nr = deg - t0;
                float wv[8]; float2 raw[8];
#pragma unroll
                for (int k = 0; k < 8; ++k) {
                    if (k < nr) {
                        int s2 = lds_col[wid][t0 + k];
                        wv[k] = lds_alpha[wid][t0 + k][head];
                        raw[k] = *(const float2*)&hh[(size_t)s2 * HC + lane * 4];
                    } else {
                        wv[k] = 0.f;
                        raw[k] = make_float2(0.f, 0.f);
                    }
                }
#pragma unroll
                for (int k = 0; k < 8; ++k) {
                    float2 f0 = __half22float2(*(__half2*)&raw[k].x);
                    float2 f1 = __half22float2(*(__half2*)&raw[k].y);
                    ax = fmaf(wv[k], f0.x, ax); ay = fmaf(wv[k], f0.y, ay);
                    az = fmaf(wv[k], f1.x, az); aw = fmaf(wv[k], f1.y, aw);
                }
            }
        } else {
            float m0 = -1e30f, m1 = -1e30f, m2 = -1e30f, m3 = -1e30f;
            for (int j = start + lane; j < end; j += 64) {
                int s = col[j];
                float4 as = *(const float4*)&al_s[s * 4];
                float e0 = as.x + ald.x; e0 = e0 > 0.f ? e0 : SLOPE * e0;
                float e1 = as.y + ald.y; e1 = e1 > 0.f ? e1 : SLOPE * e1;
                float e2 = as.z + ald.z; e2 = e2 > 0.f ? e2 : SLOPE * e2;
                float e3 = as.w + ald.w; e3 = e3 > 0.f ? e3 : SLOPE * e3;
                m0 = fmaxf(m0, e0); m1 = fmaxf(m1, e1);
                m2 = fmaxf(m2, e2); m3 = fmaxf(m3, e3);
            }
#pragma unroll
            for (int off = 1; off < 64; off <<= 1) {
                m0 = fmaxf(m0, __shfl_xor(m0, off, 64));
                m1 = fmaxf(m1, __shfl_xor(m1, off, 64));
                m2 = fmaxf(m2, __shfl_xor(m2, off, 64));
                m3 = fmaxf(m3, __shfl_xor(m3, off, 64));
            }
            float d0 = 0.f, d1 = 0.f, d2 = 0.f, d3 = 0.f;
            for (int j = start + lane; j < end; j += 64) {
                int s = col[j];
                float4 as = *(const float4*)&al_s[s * 4];
                float e0 = as.x + ald.x; e0 = e0 > 0.f ? e0 : SLOPE * e0;
                float e1 = as.y + ald.y; e1 = e1 > 0.f ? e1 : SLOPE * e1;
                float e2 = as.z + ald.z; e2 = e2 > 0.f ? e2 : SLOPE * e2;
                float e3 = as.w + ald.w; e3 = e3 > 0.f ? e3 : SLOPE * e3;
                d0 += expf(e0 - m0); d1 += expf(e1 - m1);
                d2 += expf(e2 - m2); d3 += expf(e3 - m3);
            }
#pragma unroll
            for (int off = 1; off < 64; off <<= 1) {
                d0 += __shfl_xor(d0, off, 64);
                d1 += __shfl_xor(d1, off, 64);
                d2 += __shfl_xor(d2, off, 64);
                d3 += __shfl_xor(d3, off, 64);
            }
            float inv0 = 1.f / (d0 + 1e-16f), inv1 = 1.f / (d1 + 1e-16f);
            float inv2 = 1.f / (d2 + 1e-16f), inv3 = 1.f / (d3 + 1e-16f);
            float m_h   = head == 0 ? m0   : head == 1 ? m1   : head == 2 ? m2   : m3;
            float inv_h = head == 0 ? inv0 : head == 1 ? inv1 : head == 2 ? inv2 : inv3;
            for (int jb = start; jb < end; jb += 64) {
                int j = jb + lane;
                int cs = (j < end) ? col[j] : 0;
                int cnt2 = min(64, end - jb);
                for (int t = 0; t < cnt2; ++t) {
                    int s = __shfl(cs, t, 64);
                    float als2 = al_s[s * 4 + head];
                    float e = als2 + ald_h; e = e > 0.f ? e : SLOPE * e;
                    float wv = expf(e - m_h) * inv_h;
                    float2 raw = *(const float2*)&hh[(size_t)s * HC + lane * 4];
                    float2 f0 = __half22float2(*(__half2*)&raw.x);
                    float2 f1 = __half22float2(*(__half2*)&raw.y);
                    ax = fmaf(wv, f0.x, ax); ay = fmaf(wv, f0.y, ay);
                    az = fmaf(wv, f1.x, az); aw = fmaf(wv, f1.y, aw);
                }
            }
        }

        if (mode == 0) {
            float4 b4 = *(const float4*)&bias[lane * 4];
            float vx = ax + b4.x; vx = vx > 0.f ? vx : expm1f(vx);
            float vy = ay + b4.y; vy = vy > 0.f ? vy : expm1f(vy);
            float vz = az + b4.z; vz = vz > 0.f ? vz : expm1f(vz);
            float vw = aw + b4.w; vw = vw > 0.f ? vw : expm1f(vw);
            _Float16 v[4] = {(_Float16)vx, (_Float16)vy, (_Float16)vz, (_Float16)vw};
            *(float2*)&out_h[(size_t)node * HC + lane * 4] = *(float2*)v;   // 8B
        } else {
#pragma unroll
            for (int off = 16; off < 64; off <<= 1) {
                ax += __shfl_xor(ax, off, 64);
                ay += __shfl_xor(ay, off, 64);
                az += __shfl_xor(az, off, 64);
                aw += __shfl_xor(aw, off, 64);
            }
            if (lane < 16) {
                float4 b4 = *(const float4*)&bias[lane * 4];
                float4 v = make_float4(ax * 0.25f + b4.x, ay * 0.25f + b4.y,
                                       az * 0.25f + b4.z, aw * 0.25f + b4.w);
                *(float4*)&out_f[(size_t)node * 64 + lane * 4] = v;
            }
        }
    }
}

// ---------------- fused pool + MLP --------------------------------------------
__global__ __launch_bounds__(1024) void poolmlp_kernel(const float* __restrict__ act,
        const int* __restrict__ batch,
        const float* __restrict__ pW1, const float* __restrict__ pb1,
        const float* __restrict__ pW2, const float* __restrict__ pb2,
        float* __restrict__ outp) {
    __shared__ float part[16][64];
    __shared__ float p[64];
    __shared__ float z[32];
    int b = blockIdx.x;
    int warp = threadIdx.x >> 6;
    int lane = threadIdx.x & 63;
    int lo = 0, hi = N_NODES;
    while (lo < hi) { int mid = (lo + hi) >> 1; if (batch[mid] < b) lo = mid + 1; else hi = mid; }
    int s = lo;
    lo = 0; hi = N_NODES;
    while (lo < hi) { int mid = (lo + hi) >> 1; if (batch[mid] < b + 1) lo = mid + 1; else hi = mid; }
    int e = lo;
    float sum = 0.f;
    for (int n = s + warp; n < e; n += 16)
        sum += act[(size_t)n * 64 + lane];
    part[warp][lane] = sum;
    __syncthreads();
    int t = threadIdx.x;
    if (t < 64) {
        float tt = 0.f;
#pragma unroll
        for (int r = 0; r < 16; ++r) tt += part[r][t];
        p[t] = tt / (float)max(e - s, 1);
    }
    __syncthreads();
    if (t < 32) {
        float s2 = pb1[t];
        for (int c = 0; c < 64; ++c) s2 += p[c] * pW1[c * 32 + t];
        z[t] = s2 > 0.f ? s2 : 0.f;
    }
    __syncthreads();
    if (t < OUT_DIM) {
        float s2 = pb2[t];
        for (int k = 0; k < 32; ++k) s2 += z[k] * pW2[k * 10 + t];
        outp[b * 10 + t] = s2;
    }
}

// ---------------- launch ------------------------------------------------------
extern "C" void kernel_launch(void* const* d_in, const int* in_sizes, int n_in,
                              void* d_out, int out_size, void* d_ws, size_t ws_size,
                              hipStream_t stream) {
    const float* x    = (const float*)d_in[0];
    const int*   ei   = (const int*)d_in[1];
    const int*   batch= (const int*)d_in[2];
    const float* W0   = (const float*)d_in[3];
    const float* b0   = (const float*)d_in[4];
    const float* as0  = (const float*)d_in[5];
    const float* ad0  = (const float*)d_in[6];
    const float* W1   = (const float*)d_in[7];
    const float* b1   = (const float*)d_in[8];
    const float* as1  = (const float*)d_in[9];
    const float* ad1  = (const float*)d_in[10];
    const float* W2   = (const float*)d_in[11];
    const float* b2   = (const float*)d_in[12];
    const float* as2  = (const float*)d_in[13];
    const float* ad2  = (const float*)d_in[14];
    const float* pW1  = (const float*)d_in[15];
    const float* pb1  = (const float*)d_in[16];
    const float* pW2  = (const float*)d_in[17];
    const float* pb2  = (const float*)d_in[18];
    float* out = (float*)d_out;

    char* ws = (char*)d_ws;
    size_t off = 0;
    auto alloc = [&](size_t bytes) -> void* {
        void* p = ws + off;
        off += (bytes + 255) & ~(size_t)255;
        return p;
    };
    __half*    h_half = (__half*)alloc((size_t)N_NODES * HC * 2);
    _Float16*  act_h  = (_Float16*)alloc((size_t)N_NODES * HC * 2);
    float*     act_f  = (float*)alloc((size_t)N_NODES * 64 * 4);
    _Float16*  xhi    = (_Float16*)alloc((size_t)N_NODES * 128 * 2);
    _Float16*  xlo    = (_Float16*)alloc((size_t)N_NODES * 128 * 2);
    float* als    = (float*)alloc((size_t)N_NODES * 4 * 4);
    float* ald    = (float*)alloc((size_t)N_NODES * 4 * 4);
    int*   cnt    = (int*)alloc((size_t)N_NODES * 4);
    int*   row_ptr= (int*)alloc((size_t)(N_NODES + 1) * 4);
    int*   cursor = (int*)alloc((size_t)N_NODES * 4);
    int*   col    = (int*)alloc((size_t)(E_EDGES + N_NODES) * 4);
    float* pooled = (float*)alloc((size_t)B_GR * 64 * 4);
    int*   bsum   = (int*)alloc((size_t)NBLK_SCAN * 4);
    int*   boff   = (int*)alloc((size_t)NBLK_SCAN * 4);
    _Float16* w0h = (_Float16*)alloc((size_t)128 * 256 * 2);
    _Float16* w0l = (_Float16*)alloc((size_t)128 * 256 * 2);
    _Float16* w1h = (_Float16*)alloc((size_t)256 * 256 * 2);
    _Float16* w1l = (_Float16*)alloc((size_t)256 * 256 * 2);
    _Float16* w2h = (_Float16*)alloc((size_t)256 * 256 * 2);
    _Float16* w2l = (_Float16*)alloc((size_t)256 * 256 * 2);

    const int* srcs = ei;
    const int* dsts = ei + E_EDGES;

    // fused prep: x split + 3 W splits + cnt=1 init
    const int PREP_N = N_NODES * 128 + 128 * 256 + 256 * 256 + 256 * 256 + N_NODES;
    prep_split<<<(PREP_N + 255) / 256, 256, 0, stream>>>(
        x, xhi, xlo, W0, w0h, w0l, W1, w1h, w1l, W2, w2h, w2l, cnt);

    // CSR by dst (graph static within call; reused by all 3 layers)
    hist_kernel<<<(E_EDGES + 255) / 256, 256, 0, stream>>>(dsts, cnt);
    scan_bsum<<<NBLK_SCAN, 256, 0, stream>>>(cnt, bsum);
    scan_boff<<<1, 256, 0, stream>>>(bsum, boff);
    scan_final<<<NBLK_SCAN, 256, 0, stream>>>(cnt, boff, row_ptr, cursor);
    scatter_kernel<<<(E_EDGES + N_NODES + 255) / 256, 256, 0, stream>>>(srcs, dsts, cursor, col);

    int gblk = (N_NODES + 63) / 64;   // 782
    int nblk = (N_NODES + 7) / 8;     // 6250

    // layer 0 (A = x split hi/lo: 3-term)
    gemm16<128, 3><<<gblk, 256, 0, stream>>>(xhi, xlo, w0h, w0l, h_half, as0, ad0, als, ald, N_NODES);
    agg_kernel<<<nblk, 256, 0, stream>>>(h_half, als, ald, row_ptr, col, b0, act_h, act_f, 0);
    // layer 1 (A = act fp16 exact: 2-term)
    gemm16<256, 2><<<gblk, 256, 0, stream>>>(act_h, nullptr, w1h, w1l, h_half, as1, ad1, als, ald, N_NODES);
    agg_kernel<<<nblk, 256, 0, stream>>>(h_half, als, ald, row_ptr, col, b1, act_h, act_f, 0);
    // layer 2 (mean heads, no ELU, fp32 out)
    gemm16<256, 2><<<gblk, 256, 0, stream>>>(act_h, nullptr, w2h, w2l, h_half, as2, ad2, als, ald, N_NODES);
    agg_kernel<<<nblk, 256, 0, stream>>>(h_half, als, ald, row_ptr, col, b2, act_h, act_f, 1);

    poolmlp_kernel<<<B_GR, 1024, 0, stream>>>(act_f, batch, pW1, pb1, pW2, pb2, out);
}

// Round 12
// 421.795 us; speedup vs baseline: 1.1311x; 1.0213x over previous
//
#include <hip/hip_runtime.h>
#include <hip/hip_fp16.h>
#include <cstdint>

#define N_NODES 50000
#define E_EDGES 800000
#define HC 256           // H*C
#define B_GR 64
#define OUT_DIM 10
#define SLOPE 0.2f
#define NBLK_SCAN ((N_NODES + 255) / 256)   // 196

using f16x8 = __attribute__((ext_vector_type(8))) _Float16;
using f32x4 = __attribute__((ext_vector_type(4))) float;

#define GLOAD_LDS16(gsrc, ldst) \
    __builtin_amdgcn_global_load_lds((const __attribute__((address_space(1))) void*)(gsrc), \
        (__attribute__((address_space(3))) void*)(ldst), 16, 0, 0)

// ---------------- prep: x->hi/lo; W0/1/2 -> fragment-major hi/lo; cnt=1 -------
__device__ inline void wsplit_one(const float* W, _Float16* wh, _Float16* wl,
                                  int K, int i) {
    int k = i >> 8, n = i & 255;
    float v = W[i];
    _Float16 h = (_Float16)v;
    _Float16 l = (_Float16)(v - (float)h);
    int oidx = ((((k >> 5) * 256 + n) * 4) + ((k >> 3) & 3)) * 8 + (k & 7);
    wh[oidx] = h;
    wl[oidx] = l;
}

__global__ void prep_split(const float* __restrict__ x,
        _Float16* __restrict__ xhi, _Float16* __restrict__ xlo,
        const float* __restrict__ W0, _Float16* __restrict__ w0h, _Float16* __restrict__ w0l,
        const float* __restrict__ W1, _Float16* __restrict__ w1h, _Float16* __restrict__ w1l,
        const float* __restrict__ W2, _Float16* __restrict__ w2h, _Float16* __restrict__ w2l,
        int* __restrict__ cnt) {
    const int NX = N_NODES * 128;
    int i = blockIdx.x * 256 + threadIdx.x;
    if (i < NX) {
        float v = x[i];
        _Float16 h = (_Float16)v;
        xhi[i] = h;
        xlo[i] = (_Float16)(v - (float)h);
        return;
    }
    int j = i - NX;
    if (j < 128 * 256) { wsplit_one(W0, w0h, w0l, 128, j); return; }
    j -= 128 * 256;
    if (j < 256 * 256) { wsplit_one(W1, w1h, w1l, 256, j); return; }
    j -= 256 * 256;
    if (j < 256 * 256) { wsplit_one(W2, w2h, w2l, 256, j); return; }
    j -= 256 * 256;
    if (j < N_NODES) cnt[j] = 1;    // self-loop pre-count
}

// ---------------- MFMA GEMM: A split hi/lo fp16 (3-term) or exact (2-term) ----
template<int K, int TERMS>
__global__ __launch_bounds__(256) void gemm16(const _Float16* __restrict__ Ahi,
        const _Float16* __restrict__ Alo,
        const _Float16* __restrict__ wt_hi, const _Float16* __restrict__ wt_lo,
        __half* __restrict__ h_half,
        const float* __restrict__ a_src, const float* __restrict__ a_dst,
        float* __restrict__ al_s, float* __restrict__ al_d, int M) {
    __shared__ _Float16 abuf[2][2][64][64];
    int tid = threadIdx.x;
    int w = tid >> 6;
    int l = tid & 63;
    int rr = l & 15;
    int kg = l >> 4;
    int row0 = blockIdx.x * 64;
    int srow = tid >> 3;
    int sgs  = tid & 7;

    f32x4 acc[4][4] = {};
    const int NT = K / 64;

    auto stage = [&](int buf, int t) {
        int k0 = t * 64;
#pragma unroll
        for (int i = 0; i < 2; ++i) {
            int row = i * 32 + srow;
            int g = sgs ^ (row & 7);
            int gr = min(row0 + row, M - 1);
            char* dst = (char*)abuf + buf * 16384 + i * 4096 + w * 1024;
            GLOAD_LDS16(&Ahi[(size_t)gr * K + k0 + g * 8], dst);
            if constexpr (TERMS == 3)
                GLOAD_LDS16(&Alo[(size_t)gr * K + k0 + g * 8], dst + 8192);
        }
    };

    stage(0, 0);
    __syncthreads();
    int cur = 0;
    for (int t = 0; t < NT; ++t) {
        if (t + 1 < NT) stage(cur ^ 1, t + 1);
        const _Float16* base_hi = &abuf[cur][0][0][0];
        const _Float16* base_lo = &abuf[cur][1][0][0];
#pragma unroll
        for (int c = 0; c < 2; ++c) {
            f16x8 ah[4], alo_[4];
#pragma unroll
            for (int fm = 0; fm < 4; ++fm) {
                int row = fm * 16 + rr;
                int gsw = ((c * 4 + kg) ^ (row & 7));
                ah[fm] = *(const f16x8*)&base_hi[row * 64 + gsw * 8];
                if constexpr (TERMS == 3)
                    alo_[fm] = *(const f16x8*)&base_lo[row * 64 + gsw * 8];
            }
            int chunk = t * 2 + c;
#pragma unroll
            for (int fn = 0; fn < 4; ++fn) {
                int col = w * 64 + fn * 16 + rr;
                size_t boff = (((size_t)chunk * 256 + col) * 4 + kg) * 8;
                f16x8 bh = *(const f16x8*)&wt_hi[boff];
                f16x8 bl = *(const f16x8*)&wt_lo[boff];
#pragma unroll
                for (int fm = 0; fm < 4; ++fm) {
                    acc[fm][fn] = __builtin_amdgcn_mfma_f32_16x16x32_f16(ah[fm], bh, acc[fm][fn], 0, 0, 0);
                    acc[fm][fn] = __builtin_amdgcn_mfma_f32_16x16x32_f16(ah[fm], bl, acc[fm][fn], 0, 0, 0);
                    if constexpr (TERMS == 3)
                        acc[fm][fn] = __builtin_amdgcn_mfma_f32_16x16x32_f16(alo_[fm], bh, acc[fm][fn], 0, 0, 0);
                }
            }
        }
        __syncthreads();
        cur ^= 1;
    }

    int head = w;
    float asv[4], adv[4];
#pragma unroll
    for (int fn = 0; fn < 4; ++fn) {
        asv[fn] = a_src[head * 64 + fn * 16 + rr];
        adv[fn] = a_dst[head * 64 + fn * 16 + rr];
    }
#pragma unroll
    for (int fm = 0; fm < 4; ++fm) {
#pragma unroll
        for (int r = 0; r < 4; ++r) {
            int row = fm * 16 + kg * 4 + r;
            int gr = row0 + row;
            float ps = acc[fm][0][r] * asv[0] + acc[fm][1][r] * asv[1]
                     + acc[fm][2][r] * asv[2] + acc[fm][3][r] * asv[3];
            float pd = acc[fm][0][r] * adv[0] + acc[fm][1][r] * adv[1]
                     + acc[fm][2][r] * adv[2] + acc[fm][3][r] * adv[3];
#pragma unroll
            for (int off = 1; off < 16; off <<= 1) {
                ps += __shfl_xor(ps, off, 64);
                pd += __shfl_xor(pd, off, 64);
            }
            if (gr < M) {
#pragma unroll
                for (int fn = 0; fn < 4; ++fn)
                    h_half[(size_t)gr * HC + w * 64 + fn * 16 + rr] = __float2half(acc[fm][fn][r]);
                if (rr == 0) {
                    al_s[gr * 4 + head] = ps;
                    al_d[gr * 4 + head] = pd;
                }
            }
        }
    }
}

// ---------------- CSR build ---------------------------------------------------
__global__ void hist_kernel(const int* __restrict__ dsts, int* cnt) {
    int i = blockIdx.x * blockDim.x + threadIdx.x;
    if (i < E_EDGES) atomicAdd(&cnt[dsts[i]], 1);
}
__global__ __launch_bounds__(256) void scan_bsum(const int* __restrict__ cnt,
                                                 int* __restrict__ bsum) {
    __shared__ int ws[4];
    int t = threadIdx.x;
    int i = blockIdx.x * 256 + t;
    int v = (i < N_NODES) ? cnt[i] : 0;
#pragma unroll
    for (int off = 1; off < 64; off <<= 1) v += __shfl_xor(v, off, 64);
    if ((t & 63) == 0) ws[t >> 6] = v;
    __syncthreads();
    if (t == 0) bsum[blockIdx.x] = ws[0] + ws[1] + ws[2] + ws[3];
}
__global__ __launch_bounds__(256) void scan_boff(const int* __restrict__ bsum,
                                                 int* __restrict__ boff) {
    __shared__ int s[256];
    int t = threadIdx.x;
    int v = (t < NBLK_SCAN) ? bsum[t] : 0;
    s[t] = v;
    __syncthreads();
    for (int off = 1; off < 256; off <<= 1) {
        int u = (t >= off) ? s[t - off] : 0;
        __syncthreads();
        s[t] += u;
        __syncthreads();
    }
    if (t < NBLK_SCAN) boff[t] = s[t] - v;
}
__global__ __launch_bounds__(256) void scan_final(const int* __restrict__ cnt,
        const int* __restrict__ boff, int* __restrict__ row_ptr,
        int* __restrict__ cursor) {
    __shared__ int s[256];
    int b = blockIdx.x, t = threadIdx.x;
    int i = b * 256 + t;
    int v = (i < N_NODES) ? cnt[i] : 0;
    s[t] = v;
    __syncthreads();
    for (int off = 1; off < 256; off <<= 1) {
        int u = (t >= off) ? s[t - off] : 0;
        __syncthreads();
        s[t] += u;
        __syncthreads();
    }
    int rp = boff[b] + s[t] - v;
    if (i < N_NODES) { row_ptr[i] = rp; cursor[i] = rp; }
    if (i == N_NODES - 1) row_ptr[N_NODES] = rp + v;
}
__global__ void scatter_kernel(const int* __restrict__ srcs, const int* __restrict__ dsts,
                               int* cursor, int* col) {
    int i = blockIdx.x * blockDim.x + threadIdx.x;
    if (i >= E_EDGES + N_NODES) return;
    int s, d;
    if (i < E_EDGES) { s = srcs[i]; d = dsts[i]; }
    else             { s = d = i - E_EDGES; }
    int pos = atomicAdd(&cursor[d], 1);
    col[pos] = s;
}

// ---------------- per-node softmax + aggregation -----------------------------
// mode 0: concat heads, +bias[256], ELU, fp16 out (act_h).
// mode 1: mean heads, +bias[64], no ELU, fp32 out (act_f).
// Fast path: 2 nodes/wave, 4-deep pipelined gather (32 VGPR sweet spot).
__global__ __launch_bounds__(256) void agg_kernel(const __half* __restrict__ hh,
        const float* __restrict__ al_s, const float* __restrict__ al_d,
        const int* __restrict__ row_ptr, const int* __restrict__ col,
        const float* __restrict__ bias, _Float16* __restrict__ out_h,
        float* __restrict__ out_f, int mode) {
    __shared__ int   lds_col[4][64];
    __shared__ float lds_alpha[4][64][4];
    int wid  = threadIdx.x >> 6;
    int lane = threadIdx.x & 63;
    int hf   = lane >> 5;
    int ln   = lane & 31;
    int nodeA = blockIdx.x * 8 + wid * 2;   // N_NODES % 8 == 0 -> no tail
    int nodeB = nodeA + 1;
    int sA = row_ptr[nodeA], eA = row_ptr[nodeA + 1];
    int sB = row_ptr[nodeB], eB = row_ptr[nodeB + 1];
    int degA = eA - sA, degB = eB - sB;

    if (degA <= 32 && degB <= 32) {
        // ================= fast path: 2 nodes / wave =================
        int node  = hf ? nodeB : nodeA;
        int start = hf ? sB : sA;
        int deg   = hf ? degB : degA;
        int degmax = max(degA, degB);
        const float4 ald = *(const float4*)&al_d[node * 4];
        bool active = ln < deg;
        int s = active ? col[start + ln] : 0;
        float4 as = *(const float4*)&al_s[s * 4];
        float e0 = as.x + ald.x; e0 = e0 > 0.f ? e0 : SLOPE * e0;
        float e1 = as.y + ald.y; e1 = e1 > 0.f ? e1 : SLOPE * e1;
        float e2 = as.z + ald.z; e2 = e2 > 0.f ? e2 : SLOPE * e2;
        float e3 = as.w + ald.w; e3 = e3 > 0.f ? e3 : SLOPE * e3;
        float m0 = active ? e0 : -1e30f, m1 = active ? e1 : -1e30f;
        float m2 = active ? e2 : -1e30f, m3 = active ? e3 : -1e30f;
#pragma unroll
        for (int off = 1; off < 32; off <<= 1) {   // width-32: stays in half
            m0 = fmaxf(m0, __shfl_xor(m0, off, 64));
            m1 = fmaxf(m1, __shfl_xor(m1, off, 64));
            m2 = fmaxf(m2, __shfl_xor(m2, off, 64));
            m3 = fmaxf(m3, __shfl_xor(m3, off, 64));
        }
        float x0 = active ? expf(e0 - m0) : 0.f;
        float x1 = active ? expf(e1 - m1) : 0.f;
        float x2 = active ? expf(e2 - m2) : 0.f;
        float x3 = active ? expf(e3 - m3) : 0.f;
        float d0 = x0, d1 = x1, d2 = x2, d3 = x3;
#pragma unroll
        for (int off = 1; off < 32; off <<= 1) {
            d0 += __shfl_xor(d0, off, 64);
            d1 += __shfl_xor(d1, off, 64);
            d2 += __shfl_xor(d2, off, 64);
            d3 += __shfl_xor(d3, off, 64);
        }
        float4 a4;
        a4.x = x0 / (d0 + 1e-16f); a4.y = x1 / (d1 + 1e-16f);
        a4.z = x2 / (d2 + 1e-16f); a4.w = x3 / (d3 + 1e-16f);
        int e = hf * 32 + ln;
        lds_col[wid][e] = s;
        *(float4*)&lds_alpha[wid][e][0] = a4;
        int head = ln >> 3;
        int ch0 = ln * 8;
        float acc[8] = {0.f, 0.f, 0.f, 0.f, 0.f, 0.f, 0.f, 0.f};
        int ebase = hf * 32;
        for (int t0 = 0; t0 < degmax; t0 += 4) {
            float wv[4]; float4 raw[4];
#pragma unroll
            for (int k = 0; k < 4; ++k) {
                int t = t0 + k;
                int tt = min(t, deg - 1);          // deg >= 1 (self-loop)
                int s2 = lds_col[wid][ebase + tt];
                wv[k] = (t < deg) ? lds_alpha[wid][ebase + tt][head] : 0.f;
                raw[k] = *(const float4*)&hh[(size_t)s2 * HC + ch0];
            }
#pragma unroll
            for (int k = 0; k < 4; ++k) {
                const __half2* hp = (const __half2*)&raw[k];
                float2 f0 = __half22float2(hp[0]);
                float2 f1 = __half22float2(hp[1]);
                float2 f2 = __half22float2(hp[2]);
                float2 f3 = __half22float2(hp[3]);
                acc[0] = fmaf(wv[k], f0.x, acc[0]); acc[1] = fmaf(wv[k], f0.y, acc[1]);
                acc[2] = fmaf(wv[k], f1.x, acc[2]); acc[3] = fmaf(wv[k], f1.y, acc[3]);
                acc[4] = fmaf(wv[k], f2.x, acc[4]); acc[5] = fmaf(wv[k], f2.y, acc[5]);
                acc[6] = fmaf(wv[k], f3.x, acc[6]); acc[7] = fmaf(wv[k], f3.y, acc[7]);
            }
        }
        if (mode == 0) {
            float b8[8];
            *(float4*)&b8[0] = *(const float4*)&bias[ch0];
            *(float4*)&b8[4] = *(const float4*)&bias[ch0 + 4];
            _Float16 v[8];
#pragma unroll
            for (int j = 0; j < 8; ++j) {
                float t = acc[j] + b8[j];
                v[j] = (_Float16)(t > 0.f ? t : expm1f(t));
            }
            *(float4*)&out_h[(size_t)node * HC + ch0] = *(float4*)v;   // 16B
        } else {
#pragma unroll
            for (int j = 0; j < 8; ++j) {
                acc[j] += __shfl_xor(acc[j], 8, 64);
                acc[j] += __shfl_xor(acc[j], 16, 64);
            }
            if (ln < 8) {
                float v[8];
#pragma unroll
                for (int j = 0; j < 8; ++j)
                    v[j] = acc[j] * 0.25f + bias[ln * 8 + j];
                *(float4*)&out_f[(size_t)node * 64 + ln * 8]     = *(float4*)&v[0];
                *(float4*)&out_f[(size_t)node * 64 + ln * 8 + 4] = *(float4*)&v[4];
            }
        }
        return;
    }

    // ================= fallback: 1 node / wave (rare, deg>32) =================
    for (int nn = 0; nn < 2; ++nn) {
        int node = nodeA + nn;
        int start = row_ptr[node], end = row_ptr[node + 1];
        int deg = end - start;
        const float4 ald = *(const float4*)&al_d[node * 4];
        int head = lane >> 4;
        float ald_h = head == 0 ? ald.x : head == 1 ? ald.y : head == 2 ? ald.z : ald.w;
        float ax = 0.f, ay = 0.f, az = 0.f, aw = 0.f;

        if (deg <= 64) {
            int j = start + lane;
            bool active = j < end;
            int s = active ? col[j] : 0;
            float4 as = *(const float4*)&al_s[s * 4];
            float e0 = as.x + ald.x; e0 = e0 > 0.f ? e0 : SLOPE * e0;
            float e1 = as.y + ald.y; e1 = e1 > 0.f ? e1 : SLOPE * e1;
            float e2 = as.z + ald.z; e2 = e2 > 0.f ? e2 : SLOPE * e2;
            float e3 = as.w + ald.w; e3 = e3 > 0.f ? e3 : SLOPE * e3;
            float m0 = active ? e0 : -1e30f, m1 = active ? e1 : -1e30f;
            float m2 = active ? e2 : -1e30f, m3 = active ? e3 : -1e30f;
#pragma unroll
            for (int off = 1; off < 64; off <<= 1) {
                m0 = fmaxf(m0, __shfl_xor(m0, off, 64));
                m1 = fmaxf(m1, __shfl_xor(m1, off, 64));
                m2 = fmaxf(m2, __shfl_xor(m2, off, 64));
                m3 = fmaxf(m3, __shfl_xor(m3, off, 64));
            }
            float x0 = active ? expf(e0 - m0) : 0.f;
            float x1 = active ? expf(e1 - m1) : 0.f;
            float x2 = active ? expf(e2 - m2) : 0.f;
            float x3 = active ? expf(e3 - m3) : 0.f;
            float d0 = x0, d1 = x1, d2 = x2, d3 = x3;
#pragma unroll
            for (int off = 1; off < 64; off <<= 1) {
                d0 += __shfl_xor(d0, off, 64);
                d1 += __shfl_xor(d1, off, 64);
                d2 += __shfl_xor(d2, off, 64);
                d3 += __shfl_xor(d3, off, 64);
            }
            float4 a4;
            a4.x = x0 / (d0 + 1e-16f); a4.y = x1 / (d1 + 1e-16f);
            a4.z = x2 / (d2 + 1e-16f); a4.w = x3 / (d3 + 1e-16f);
            lds_col[wid][lane] = s;
            *(float4*)&lds_alpha[wid][lane][0] = a4;
            for (int t0 = 0; t0 < deg; t0 += 8) {
                int nr = deg - t0;
                float wv[8]; float2 raw[8];
#pragma unroll
                for (int k = 0; k < 8; ++k) {
                    if (k < nr) {
                        int s2 = lds_col[wid][t0 + k];
                        wv[k] = lds_alpha[wid][t0 + k][head];
                        raw[k] = *(const float2*)&hh[(size_t)s2 * HC + lane * 4];
                    } else {
                        wv[k] = 0.f;
                        raw[k] = make_float2(0.f, 0.f);
                    }
                }
#pragma unroll
                for (int k = 0; k < 8; ++k) {
                    float2 f0 = __half22float2(*(__half2*)&raw[k].x);
                    float2 f1 = __half22float2(*(__half2*)&raw[k].y);
                    ax = fmaf(wv[k], f0.x, ax); ay = fmaf(wv[k], f0.y, ay);
                    az = fmaf(wv[k], f1.x, az); aw = fmaf(wv[k], f1.y, aw);
                }
            }
        } else {
            float m0 = -1e30f, m1 = -1e30f, m2 = -1e30f, m3 = -1e30f;
            for (int j = start + lane; j < end; j += 64) {
                int s = col[j];
                float4 as = *(const float4*)&al_s[s * 4];
                float e0 = as.x + ald.x; e0 = e0 > 0.f ? e0 : SLOPE * e0;
                float e1 = as.y + ald.y; e1 = e1 > 0.f ? e1 : SLOPE * e1;
                float e2 = as.z + ald.z; e2 = e2 > 0.f ? e2 : SLOPE * e2;
                float e3 = as.w + ald.w; e3 = e3 > 0.f ? e3 : SLOPE * e3;
                m0 = fmaxf(m0, e0); m1 = fmaxf(m1, e1);
                m2 = fmaxf(m2, e2); m3 = fmaxf(m3, e3);
            }
#pragma unroll
            for (int off = 1; off < 64; off <<= 1) {
                m0 = fmaxf(m0, __shfl_xor(m0, off, 64));
                m1 = fmaxf(m1, __shfl_xor(m1, off, 64));
                m2 = fmaxf(m2, __shfl_xor(m2, off, 64));
                m3 = fmaxf(m3, __shfl_xor(m3, off, 64));
            }
            float d0 = 0.f, d1 = 0.f, d2 = 0.f, d3 = 0.f;
            for (int j = start + lane; j < end; j += 64) {
                int s = col[j];
                float4 as = *(const float4*)&al_s[s * 4];
                float e0 = as.x + ald.x; e0 = e0 > 0.f ? e0 : SLOPE * e0;
                float e1 = as.y + ald.y; e1 = e1 > 0.f ? e1 : SLOPE * e1;
                float e2 = as.z + ald.z; e2 = e2 > 0.f ? e2 : SLOPE * e2;
                float e3 = as.w + ald.w; e3 = e3 > 0.f ? e3 : SLOPE * e3;
                d0 += expf(e0 - m0); d1 += expf(e1 - m1);
                d2 += expf(e2 - m2); d3 += expf(e3 - m3);
            }
#pragma unroll
            for (int off = 1; off < 64; off <<= 1) {
                d0 += __shfl_xor(d0, off, 64);
                d1 += __shfl_xor(d1, off, 64);
                d2 += __shfl_xor(d2, off, 64);
                d3 += __shfl_xor(d3, off, 64);
            }
            float inv0 = 1.f / (d0 + 1e-16f), inv1 = 1.f / (d1 + 1e-16f);
            float inv2 = 1.f / (d2 + 1e-16f), inv3 = 1.f / (d3 + 1e-16f);
            float m_h   = head == 0 ? m0   : head == 1 ? m1   : head == 2 ? m2   : m3;
            float inv_h = head == 0 ? inv0 : head == 1 ? inv1 : head == 2 ? inv2 : inv3;
            for (int jb = start; jb < end; jb += 64) {
                int j = jb + lane;
                int cs = (j < end) ? col[j] : 0;
                int cnt2 = min(64, end - jb);
                for (int t = 0; t < cnt2; ++t) {
                    int s = __shfl(cs, t, 64);
                    float als2 = al_s[s * 4 + head];
                    float e = als2 + ald_h; e = e > 0.f ? e : SLOPE * e;
                    float wv = expf(e - m_h) * inv_h;
                    float2 raw = *(const float2*)&hh[(size_t)s * HC + lane * 4];
                    float2 f0 = __half22float2(*(__half2*)&raw.x);
                    float2 f1 = __half22float2(*(__half2*)&raw.y);
                    ax = fmaf(wv, f0.x, ax); ay = fmaf(wv, f0.y, ay);
                    az = fmaf(wv, f1.x, az); aw = fmaf(wv, f1.y, aw);
                }
            }
        }

        if (mode == 0) {
            float4 b4 = *(const float4*)&bias[lane * 4];
            float vx = ax + b4.x; vx = vx > 0.f ? vx : expm1f(vx);
            float vy = ay + b4.y; vy = vy > 0.f ? vy : expm1f(vy);
            float vz = az + b4.z; vz = vz > 0.f ? vz : expm1f(vz);
            float vw = aw + b4.w; vw = vw > 0.f ? vw : expm1f(vw);
            _Float16 v[4] = {(_Float16)vx, (_Float16)vy, (_Float16)vz, (_Float16)vw};
            *(float2*)&out_h[(size_t)node * HC + lane * 4] = *(float2*)v;   // 8B
        } else {
#pragma unroll
            for (int off = 16; off < 64; off <<= 1) {
                ax += __shfl_xor(ax, off, 64);
                ay += __shfl_xor(ay, off, 64);
                az += __shfl_xor(az, off, 64);
                aw += __shfl_xor(aw, off, 64);
            }
            if (lane < 16) {
                float4 b4 = *(const float4*)&bias[lane * 4];
                float4 v = make_float4(ax * 0.25f + b4.x, ay * 0.25f + b4.y,
                                       az * 0.25f + b4.z, aw * 0.25f + b4.w);
                *(float4*)&out_f[(size_t)node * 64 + lane * 4] = v;
            }
        }
    }
}

// ---------------- fused pool + MLP --------------------------------------------
__global__ __launch_bounds__(1024) void poolmlp_kernel(const float* __restrict__ act,
        const int* __restrict__ batch,
        const float* __restrict__ pW1, const float* __restrict__ pb1,
        const float* __restrict__ pW2, const float* __restrict__ pb2,
        float* __restrict__ outp) {
    __shared__ float part[16][64];
    __shared__ float p[64];
    __shared__ float z[32];
    int b = blockIdx.x;
    int warp = threadIdx.x >> 6;
    int lane = threadIdx.x & 63;
    int lo = 0, hi = N_NODES;
    while (lo < hi) { int mid = (lo + hi) >> 1; if (batch[mid] < b) lo = mid + 1; else hi = mid; }
    int s = lo;
    lo = 0; hi = N_NODES;
    while (lo < hi) { int mid = (lo + hi) >> 1; if (batch[mid] < b + 1) lo = mid + 1; else hi = mid; }
    int e = lo;
    float sum = 0.f;
    for (int n = s + warp; n < e; n += 16)
        sum += act[(size_t)n * 64 + lane];
    part[warp][lane] = sum;
    __syncthreads();
    int t = threadIdx.x;
    if (t < 64) {
        float tt = 0.f;
#pragma unroll
        for (int r = 0; r < 16; ++r) tt += part[r][t];
        p[t] = tt / (float)max(e - s, 1);
    }
    __syncthreads();
    if (t < 32) {
        float s2 = pb1[t];
        for (int c = 0; c < 64; ++c) s2 += p[c] * pW1[c * 32 + t];
        z[t] = s2 > 0.f ? s2 : 0.f;
    }
    __syncthreads();
    if (t < OUT_DIM) {
        float s2 = pb2[t];
        for (int k = 0; k < 32; ++k) s2 += z[k] * pW2[k * 10 + t];
        outp[b * 10 + t] = s2;
    }
}

// ---------------- launch ------------------------------------------------------
extern "C" void kernel_launch(void* const* d_in, const int* in_sizes, int n_in,
                              void* d_out, int out_size, void* d_ws, size_t ws_size,
                              hipStream_t stream) {
    const float* x    = (const float*)d_in[0];
    const int*   ei   = (const int*)d_in[1];
    const int*   batch= (const int*)d_in[2];
    const float* W0   = (const float*)d_in[3];
    const float* b0   = (const float*)d_in[4];
    const float* as0  = (const float*)d_in[5];
    const float* ad0  = (const float*)d_in[6];
    const float* W1   = (const float*)d_in[7];
    const float* b1   = (const float*)d_in[8];
    const float* as1  = (const float*)d_in[9];
    const float* ad1  = (const float*)d_in[10];
    const float* W2   = (const float*)d_in[11];
    const float* b2   = (const float*)d_in[12];
    const float* as2  = (const float*)d_in[13];
    const float* ad2  = (const float*)d_in[14];
    const float* pW1  = (const float*)d_in[15];
    const float* pb1  = (const float*)d_in[16];
    const float* pW2  = (const float*)d_in[17];
    const float* pb2  = (const float*)d_in[18];
    float* out = (float*)d_out;

    char* ws = (char*)d_ws;
    size_t off = 0;
    auto alloc = [&](size_t bytes) -> void* {
        void* p = ws + off;
        off += (bytes + 255) & ~(size_t)255;
        return p;
    };
    __half*    h_half = (__half*)alloc((size_t)N_NODES * HC * 2);
    _Float16*  act_h  = (_Float16*)alloc((size_t)N_NODES * HC * 2);
    float*     act_f  = (float*)alloc((size_t)N_NODES * 64 * 4);
    _Float16*  xhi    = (_Float16*)alloc((size_t)N_NODES * 128 * 2);
    _Float16*  xlo    = (_Float16*)alloc((size_t)N_NODES * 128 * 2);
    float* als    = (float*)alloc((size_t)N_NODES * 4 * 4);
    float* ald    = (float*)alloc((size_t)N_NODES * 4 * 4);
    int*   cnt    = (int*)alloc((size_t)N_NODES * 4);
    int*   row_ptr= (int*)alloc((size_t)(N_NODES + 1) * 4);
    int*   cursor = (int*)alloc((size_t)N_NODES * 4);
    int*   col    = (int*)alloc((size_t)(E_EDGES + N_NODES) * 4);
    float* pooled = (float*)alloc((size_t)B_GR * 64 * 4);
    int*   bsum   = (int*)alloc((size_t)NBLK_SCAN * 4);
    int*   boff   = (int*)alloc((size_t)NBLK_SCAN * 4);
    _Float16* w0h = (_Float16*)alloc((size_t)128 * 256 * 2);
    _Float16* w0l = (_Float16*)alloc((size_t)128 * 256 * 2);
    _Float16* w1h = (_Float16*)alloc((size_t)256 * 256 * 2);
    _Float16* w1l = (_Float16*)alloc((size_t)256 * 256 * 2);
    _Float16* w2h = (_Float16*)alloc((size_t)256 * 256 * 2);
    _Float16* w2l = (_Float16*)alloc((size_t)256 * 256 * 2);

    const int* srcs = ei;
    const int* dsts = ei + E_EDGES;

    // fused prep: x split + 3 W splits + cnt=1 init
    const int PREP_N = N_NODES * 128 + 128 * 256 + 256 * 256 + 256 * 256 + N_NODES;
    prep_split<<<(PREP_N + 255) / 256, 256, 0, stream>>>(
        x, xhi, xlo, W0, w0h, w0l, W1, w1h, w1l, W2, w2h, w2l, cnt);

    // CSR by dst (graph static within call; reused by all 3 layers)
    hist_kernel<<<(E_EDGES + 255) / 256, 256, 0, stream>>>(dsts, cnt);
    scan_bsum<<<NBLK_SCAN, 256, 0, stream>>>(cnt, bsum);
    scan_boff<<<1, 256, 0, stream>>>(bsum, boff);
    scan_final<<<NBLK_SCAN, 256, 0, stream>>>(cnt, boff, row_ptr, cursor);
    scatter_kernel<<<(E_EDGES + N_NODES + 255) / 256, 256, 0, stream>>>(srcs, dsts, cursor, col);

    int gblk = (N_NODES + 63) / 64;   // 782
    int nblk = (N_NODES + 7) / 8;     // 6250

    // layer 0 (A = x split hi/lo: 3-term)
    gemm16<128, 3><<<gblk, 256, 0, stream>>>(xhi, xlo, w0h, w0l, h_half, as0, ad0, als, ald, N_NODES);
    agg_kernel<<<nblk, 256, 0, stream>>>(h_half, als, ald, row_ptr, col, b0, act_h, act_f, 0);
    // layer 1 (A = act fp16 exact: 2-term)
    gemm16<256, 2><<<gblk, 256, 0, stream>>>(act_h, nullptr, w1h, w1l, h_half, as1, ad1, als, ald, N_NODES);
    agg_kernel<<<nblk, 256, 0, stream>>>(h_half, als, ald, row_ptr, col, b1, act_h, act_f, 0);
    // layer 2 (mean heads, no ELU, fp32 out)
    gemm16<256, 2><<<gblk, 256, 0, stream>>>(act_h, nullptr, w2h, w2l, h_half, as2, ad2, als, ald, N_NODES);
    agg_kernel<<<nblk, 256, 0, stream>>>(h_half, als, ald, row_ptr, col, b2, act_h, act_f, 1);

    poolmlp_kernel<<<B_GR, 1024, 0, stream>>>(act_f, batch, pW1, pb1, pW2, pb2, out);
}